// Round 1
// baseline (957.896 us; speedup 1.0000x reference)
//
#include <hip/hip_runtime.h>
#include <stdint.h>

#define N_NODES 100000
#define N_EDGES 1600000
#define N_GRAPHS 64
#define HDIM 128

// ---------------- utility ----------------
__global__ void zero_kernel(int* __restrict__ p, int n) {
    int i = blockIdx.x * blockDim.x + threadIdx.x;
    if (i < n) p[i] = 0;
}

// ---------------- degree / CSR build ----------------
__global__ void count_deg_kernel(const int* __restrict__ dst, int* __restrict__ cnt, int E) {
    int e = blockIdx.x * blockDim.x + threadIdx.x;
    if (e < E) atomicAdd(&cnt[dst[e]], 1);
}

__global__ void rsqrt_kernel(const int* __restrict__ cnt, float* __restrict__ dis, int n) {
    int i = blockIdx.x * blockDim.x + threadIdx.x;
    if (i < n) dis[i] = rsqrtf((float)cnt[i] + 1.0f);
}

// single-block hierarchical exclusive scan of cnt[0..n) -> row_start[0..n], row_start[n]=total
__global__ __launch_bounds__(1024) void scan_kernel(const int* __restrict__ cnt,
                                                    int* __restrict__ row_start, int n) {
    __shared__ int sums[1024];
    int tid = threadIdx.x;
    int chunk = (n + 1023) >> 10;
    int s = tid * chunk;
    int e = min(n, s + chunk);
    int sum = 0;
    for (int i = s; i < e; i++) sum += cnt[i];
    sums[tid] = sum;
    __syncthreads();
    for (int off = 1; off < 1024; off <<= 1) {
        int t = (tid >= off) ? sums[tid - off] : 0;
        __syncthreads();
        sums[tid] += t;
        __syncthreads();
    }
    int run = sums[tid] - sum;   // exclusive prefix for this chunk
    for (int i = s; i < e; i++) { row_start[i] = run; run += cnt[i]; }
    if (tid == 1023) row_start[n] = sums[1023];
}

__global__ void fill_csr_kernel(const int* __restrict__ src, const int* __restrict__ dst,
                                const int* __restrict__ row_start, int* __restrict__ pos,
                                int* __restrict__ csr_src, int E) {
    int e = blockIdx.x * blockDim.x + threadIdx.x;
    if (e >= E) return;
    int d = dst[e];
    int p = row_start[d] + atomicAdd(&pos[d], 1);
    csr_src[p] = src[e];
}

// batch is sorted; gstart[g] = first node of graph g, gstart[G] = N
__global__ void graph_bounds_kernel(const int* __restrict__ batch, int* __restrict__ gstart,
                                    int n, int G) {
    int i = blockIdx.x * blockDim.x + threadIdx.x;
    if (i >= n) return;
    int b = batch[i];
    int prev = (i == 0) ? -1 : batch[i - 1];
    for (int g = prev + 1; g <= b; ++g) gstart[g] = i;
    if (i == n - 1) {
        for (int g = b + 1; g <= G; ++g) gstart[g] = n;
    }
}

// ---------------- GEMM: C[nrows x 128] = A[nrows x 128] @ W[128 x 128] ----------------
__global__ __launch_bounds__(256) void gemm_kernel(const float* __restrict__ A,
                                                   const float* __restrict__ W,
                                                   float* __restrict__ C, int nrows) {
    __shared__ float As[64][36];    // 64 rows x 32 k, pad to 36 (keeps float4 alignment: 144B)
    __shared__ float Ws[32][128];   // 32 k x 128 cols
    int tid = threadIdx.x;
    int row0 = blockIdx.x * 64;
    int tx = tid & 31;              // cols [tx*4, tx*4+4)
    int ty = tid >> 5;              // rows [ty*8, ty*8+8)
    float4 acc[8];
#pragma unroll
    for (int r = 0; r < 8; r++) acc[r] = make_float4(0.f, 0.f, 0.f, 0.f);

    for (int kt = 0; kt < 128; kt += 32) {
        // A tile: 64x32 floats = 512 float4, 2 per thread
#pragma unroll
        for (int i = 0; i < 2; i++) {
            int f4 = tid + 256 * i;
            int r = f4 >> 3, c4 = f4 & 7;
            int grow = row0 + r;
            float4 v = make_float4(0.f, 0.f, 0.f, 0.f);
            if (grow < nrows) v = *(const float4*)(A + (size_t)grow * 128 + kt + c4 * 4);
            float* dp = &As[r][c4 * 4];
            dp[0] = v.x; dp[1] = v.y; dp[2] = v.z; dp[3] = v.w;
        }
        // W tile: 32x128 floats = 1024 float4, 4 per thread
#pragma unroll
        for (int i = 0; i < 4; i++) {
            int f4 = tid + 256 * i;
            int kr = f4 >> 5, c4 = f4 & 31;
            *(float4*)&Ws[kr][c4 * 4] = *(const float4*)(W + (size_t)(kt + kr) * 128 + c4 * 4);
        }
        __syncthreads();
#pragma unroll
        for (int k4 = 0; k4 < 32; k4 += 4) {
            float4 xv[8];
#pragma unroll
            for (int r = 0; r < 8; r++) xv[r] = *(const float4*)&As[ty * 8 + r][k4];
#pragma unroll
            for (int kk = 0; kk < 4; kk++) {
                float4 wv = *(const float4*)&Ws[k4 + kk][tx * 4];
#pragma unroll
                for (int r = 0; r < 8; r++) {
                    float xk = (&xv[r].x)[kk];
                    acc[r].x = fmaf(xk, wv.x, acc[r].x);
                    acc[r].y = fmaf(xk, wv.y, acc[r].y);
                    acc[r].z = fmaf(xk, wv.z, acc[r].z);
                    acc[r].w = fmaf(xk, wv.w, acc[r].w);
                }
            }
        }
        __syncthreads();
    }
#pragma unroll
    for (int r = 0; r < 8; r++) {
        int grow = row0 + ty * 8 + r;
        if (grow < nrows) *(float4*)(C + (size_t)grow * 128 + tx * 4) = acc[r];
    }
}

// ---------------- GCN aggregation: out[n] = relu( sum_in h[s]*dis[s]*dis[n] + h[n]*dis[n]^2 + b )
__global__ __launch_bounds__(256) void agg_kernel(const float* __restrict__ h,
                                                  const float* __restrict__ dis,
                                                  const int* __restrict__ row_start,
                                                  const int* __restrict__ csr_src,
                                                  const float* __restrict__ bias,
                                                  float* __restrict__ out, int n) {
    int node = blockIdx.x * 4 + (threadIdx.x >> 6);   // one wave64 per node
    if (node >= n) return;
    int lane = threadIdx.x & 63;
    const float2* hp = (const float2*)h;
    float dn = dis[node];
    float2 self = hp[(size_t)node * 64 + lane];
    float dn2 = dn * dn;
    float2 acc = make_float2(self.x * dn2, self.y * dn2);
    int i0 = row_start[node], i1 = row_start[node + 1];
    for (int i = i0; i < i1; i++) {
        int s = csr_src[i];
        float wgt = dis[s] * dn;
        float2 v = hp[(size_t)s * 64 + lane];
        acc.x = fmaf(v.x, wgt, acc.x);
        acc.y = fmaf(v.y, wgt, acc.y);
    }
    float2 bb = ((const float2*)bias)[lane];
    acc.x = fmaxf(acc.x + bb.x, 0.f);
    acc.y = fmaxf(acc.y + bb.y, 0.f);
    ((float2*)out)[(size_t)node * 64 + lane] = acc;
}

// ---------------- pooling: psum[g][f] += sum of h rows in graph g (batch sorted) ----------------
#define POOL_CHUNK 256
__global__ __launch_bounds__(128) void pool_kernel(const float* __restrict__ h,
                                                   const int* __restrict__ batch,
                                                   float* __restrict__ psum, int n) {
    int tid = threadIdx.x;   // feature
    int r0 = blockIdx.x * POOL_CHUNK;
    if (r0 >= n) return;
    int r1 = min(n, r0 + POOL_CHUNK);
    int cur = batch[r0];
    float acc = 0.f;
    for (int r = r0; r < r1; r++) {
        int g = batch[r];
        if (g != cur) {
            atomicAdd(&psum[cur * 128 + tid], acc);
            acc = 0.f;
            cur = g;
        }
        acc += h[(size_t)r * 128 + tid];
    }
    atomicAdd(&psum[cur * 128 + tid], acc);
}

// ---------------- fused final MLP: one block per graph ----------------
__global__ __launch_bounds__(256) void mlp_kernel(const float* __restrict__ psum,
                                                  const int* __restrict__ gstart,
                                                  const float* __restrict__ sv,
                                                  const float* __restrict__ act,
                                                  const float* __restrict__ Wf1,
                                                  const float* __restrict__ bf1,
                                                  const float* __restrict__ Wf2,
                                                  const float* __restrict__ bf2,
                                                  const float* __restrict__ Wo,
                                                  const float* __restrict__ bo,
                                                  float* __restrict__ out) {
    int g = blockIdx.x, tid = threadIdx.x;
    __shared__ float z[224];
    __shared__ float z1[256];
    __shared__ float red[256];
    if (tid < 128) {
        int c = gstart[g + 1] - gstart[g];
        float cnt = fmaxf((float)c, 1.f);
        z[tid] = psum[g * 128 + tid] / cnt;
    } else if (tid < 192) {
        z[tid] = sv[g * 64 + (tid - 128)];
    } else if (tid < 224) {
        z[tid] = act[g * 32 + (tid - 192)];
    }
    __syncthreads();
    float a = bf1[tid];
    for (int k = 0; k < 224; k++) a = fmaf(z[k], Wf1[k * 256 + tid], a);
    z1[tid] = fmaxf(a, 0.f);
    __syncthreads();
    float b = bf2[tid];
    for (int k = 0; k < 256; k++) b = fmaf(z1[k], Wf2[k * 256 + tid], b);
    b = fmaxf(b, 0.f);
    red[tid] = b * Wo[tid];
    __syncthreads();
    for (int off = 128; off > 0; off >>= 1) {
        if (tid < off) red[tid] += red[tid + off];
        __syncthreads();
    }
    if (tid == 0) out[g] = red[0] + bo[0];
}

// ---------------- launch ----------------
extern "C" void kernel_launch(void* const* d_in, const int* in_sizes, int n_in,
                              void* d_out, int out_size, void* d_ws, size_t ws_size,
                              hipStream_t stream) {
    const float* x   = (const float*)d_in[0];
    const int*   eidx = (const int*)d_in[1];
    const int*   batch = (const int*)d_in[2];
    const float* sv  = (const float*)d_in[3];
    const float* act = (const float*)d_in[4];
    const float* W1  = (const float*)d_in[5];
    const float* b1  = (const float*)d_in[6];
    const float* W2  = (const float*)d_in[7];
    const float* b2  = (const float*)d_in[8];
    const float* Wf1 = (const float*)d_in[9];
    const float* bf1 = (const float*)d_in[10];
    const float* Wf2 = (const float*)d_in[11];
    const float* bf2 = (const float*)d_in[12];
    const float* Wo  = (const float*)d_in[13];
    const float* bo  = (const float*)d_in[14];
    float* out = (float*)d_out;

    const int* srcp = eidx;             // edge_index[0]
    const int* dstp = eidx + N_EDGES;   // edge_index[1]

    char* w = (char*)d_ws;
    int* deg_cnt = (int*)w;            w += (size_t)N_NODES * 4;
    int* edge_pos = (int*)w;           w += (size_t)N_NODES * 4;
    float* psum = (float*)w;           w += (size_t)N_GRAPHS * HDIM * 4;
    int* row_start = (int*)w;          w += (size_t)(N_NODES + 1) * 4;
    float* dis = (float*)w;            w += (size_t)N_NODES * 4;
    int* gstart = (int*)w;             w += (size_t)(N_GRAPHS + 1) * 4;
    int* csr_src = (int*)w;            w += (size_t)N_EDGES * 4;
    w = (char*)(((uintptr_t)w + 15) & ~(uintptr_t)15);
    float* hbuf = (float*)w;           w += (size_t)N_NODES * HDIM * 4;
    float* abuf = (float*)w;           w += (size_t)N_NODES * HDIM * 4;

    // zero deg_cnt + edge_pos + psum (contiguous)
    int zero_n = 2 * N_NODES + N_GRAPHS * HDIM;
    zero_kernel<<<(zero_n + 255) / 256, 256, 0, stream>>>(deg_cnt, zero_n);
    count_deg_kernel<<<(N_EDGES + 255) / 256, 256, 0, stream>>>(dstp, deg_cnt, N_EDGES);
    rsqrt_kernel<<<(N_NODES + 255) / 256, 256, 0, stream>>>(deg_cnt, dis, N_NODES);
    scan_kernel<<<1, 1024, 0, stream>>>(deg_cnt, row_start, N_NODES);
    fill_csr_kernel<<<(N_EDGES + 255) / 256, 256, 0, stream>>>(srcp, dstp, row_start, edge_pos, csr_src, N_EDGES);
    graph_bounds_kernel<<<(N_NODES + 255) / 256, 256, 0, stream>>>(batch, gstart, N_NODES, N_GRAPHS);

    int gemm_blocks = (N_NODES + 63) / 64;
    int agg_blocks = (N_NODES + 3) / 4;

    // conv1: h = x @ W1 ; agg+bias+relu -> abuf
    gemm_kernel<<<gemm_blocks, 256, 0, stream>>>(x, W1, hbuf, N_NODES);
    agg_kernel<<<agg_blocks, 256, 0, stream>>>(hbuf, dis, row_start, csr_src, b1, abuf, N_NODES);
    // conv2: h = abuf @ W2 ; agg+bias+relu -> abuf
    gemm_kernel<<<gemm_blocks, 256, 0, stream>>>(abuf, W2, hbuf, N_NODES);
    agg_kernel<<<agg_blocks, 256, 0, stream>>>(hbuf, dis, row_start, csr_src, b2, abuf, N_NODES);

    // pool + MLP
    pool_kernel<<<(N_NODES + POOL_CHUNK - 1) / POOL_CHUNK, 128, 0, stream>>>(abuf, batch, psum, N_NODES);
    mlp_kernel<<<N_GRAPHS, 256, 0, stream>>>(psum, gstart, sv, act, Wf1, bf1, Wf2, bf2, Wo, bo, out);
}

// Round 2
// 931.214 us; speedup vs baseline: 1.0287x; 1.0287x over previous
//
#include <hip/hip_runtime.h>
#include <hip/hip_bf16.h>
#include <stdint.h>

#define N_NODES 100000
#define N_EDGES 1600000
#define N_GRAPHS 64
#define HDIM 128

// ---------------- utility ----------------
__global__ void zero_kernel(int* __restrict__ p, int n) {
    int i = blockIdx.x * blockDim.x + threadIdx.x;
    if (i < n) p[i] = 0;
}

// ---------------- degree / CSR build ----------------
__global__ void count_deg_kernel(const int* __restrict__ dst, int* __restrict__ cnt, int E) {
    int e = blockIdx.x * blockDim.x + threadIdx.x;
    if (e < E) atomicAdd(&cnt[dst[e]], 1);
}

__global__ void rsqrt_kernel(const int* __restrict__ cnt, float* __restrict__ dis, int n) {
    int i = blockIdx.x * blockDim.x + threadIdx.x;
    if (i < n) dis[i] = rsqrtf((float)cnt[i] + 1.0f);
}

// single-block hierarchical exclusive scan of cnt[0..n) -> row_start[0..n], row_start[n]=total
__global__ __launch_bounds__(1024) void scan_kernel(const int* __restrict__ cnt,
                                                    int* __restrict__ row_start, int n) {
    __shared__ int sums[1024];
    int tid = threadIdx.x;
    int chunk = (n + 1023) >> 10;
    int s = tid * chunk;
    int e = min(n, s + chunk);
    int sum = 0;
    for (int i = s; i < e; i++) sum += cnt[i];
    sums[tid] = sum;
    __syncthreads();
    for (int off = 1; off < 1024; off <<= 1) {
        int t = (tid >= off) ? sums[tid - off] : 0;
        __syncthreads();
        sums[tid] += t;
        __syncthreads();
    }
    int run = sums[tid] - sum;   // exclusive prefix for this chunk
    for (int i = s; i < e; i++) { row_start[i] = run; run += cnt[i]; }
    if (tid == 1023) row_start[n] = sums[1023];
}

__global__ void fill_csr_kernel(const int* __restrict__ src, const int* __restrict__ dst,
                                const int* __restrict__ row_start, int* __restrict__ pos,
                                int* __restrict__ csr_src, int E) {
    int e = blockIdx.x * blockDim.x + threadIdx.x;
    if (e >= E) return;
    int d = dst[e];
    int p = row_start[d] + atomicAdd(&pos[d], 1);
    csr_src[p] = src[e];
}

// batch is sorted; gstart[g] = first node of graph g, gstart[G] = N
__global__ void graph_bounds_kernel(const int* __restrict__ batch, int* __restrict__ gstart,
                                    int n, int G) {
    int i = blockIdx.x * blockDim.x + threadIdx.x;
    if (i >= n) return;
    int b = batch[i];
    int prev = (i == 0) ? -1 : batch[i - 1];
    for (int g = prev + 1; g <= b; ++g) gstart[g] = i;
    if (i == n - 1) {
        for (int g = b + 1; g <= G; ++g) gstart[g] = n;
    }
}

// ---------------- GEMM: C[r][c] = (sum_k A[r][k] W[k][c]) * scale[r], bf16 output ----------------
__global__ __launch_bounds__(256) void gemm_kernel(const float* __restrict__ A,
                                                   const float* __restrict__ W,
                                                   const float* __restrict__ scale,
                                                   __hip_bfloat16* __restrict__ C, int nrows) {
    __shared__ float As[64][36];    // 64 rows x 32 k, pad to 36
    __shared__ float Ws[32][128];   // 32 k x 128 cols
    int tid = threadIdx.x;
    int row0 = blockIdx.x * 64;
    int tx = tid & 31;              // cols [tx*4, tx*4+4)
    int ty = tid >> 5;              // rows [ty*8, ty*8+8)
    float4 acc[8];
#pragma unroll
    for (int r = 0; r < 8; r++) acc[r] = make_float4(0.f, 0.f, 0.f, 0.f);

    for (int kt = 0; kt < 128; kt += 32) {
#pragma unroll
        for (int i = 0; i < 2; i++) {
            int f4 = tid + 256 * i;
            int r = f4 >> 3, c4 = f4 & 7;
            int grow = row0 + r;
            float4 v = make_float4(0.f, 0.f, 0.f, 0.f);
            if (grow < nrows) v = *(const float4*)(A + (size_t)grow * 128 + kt + c4 * 4);
            float* dp = &As[r][c4 * 4];
            dp[0] = v.x; dp[1] = v.y; dp[2] = v.z; dp[3] = v.w;
        }
#pragma unroll
        for (int i = 0; i < 4; i++) {
            int f4 = tid + 256 * i;
            int kr = f4 >> 5, c4 = f4 & 31;
            *(float4*)&Ws[kr][c4 * 4] = *(const float4*)(W + (size_t)(kt + kr) * 128 + c4 * 4);
        }
        __syncthreads();
#pragma unroll
        for (int k4 = 0; k4 < 32; k4 += 4) {
            float4 xv[8];
#pragma unroll
            for (int r = 0; r < 8; r++) xv[r] = *(const float4*)&As[ty * 8 + r][k4];
#pragma unroll
            for (int kk = 0; kk < 4; kk++) {
                float4 wv = *(const float4*)&Ws[k4 + kk][tx * 4];
#pragma unroll
                for (int r = 0; r < 8; r++) {
                    float xk = (&xv[r].x)[kk];
                    acc[r].x = fmaf(xk, wv.x, acc[r].x);
                    acc[r].y = fmaf(xk, wv.y, acc[r].y);
                    acc[r].z = fmaf(xk, wv.z, acc[r].z);
                    acc[r].w = fmaf(xk, wv.w, acc[r].w);
                }
            }
        }
        __syncthreads();
    }
#pragma unroll
    for (int r = 0; r < 8; r++) {
        int grow = row0 + ty * 8 + r;
        if (grow < nrows) {
            float s = scale[grow];
            __hip_bfloat162 p0 = __float22bfloat162_rn(make_float2(acc[r].x * s, acc[r].y * s));
            __hip_bfloat162 p1 = __float22bfloat162_rn(make_float2(acc[r].z * s, acc[r].w * s));
            uint2 pk;
            pk.x = *(unsigned int*)&p0;
            pk.y = *(unsigned int*)&p1;
            *(uint2*)(C + (size_t)grow * 128 + tx * 4) = pk;
        }
    }
}

// ---------------- GCN aggregation over pre-scaled bf16 h ----------------
// h_scaled[n] = (h[n] * dis[n]) in bf16.
// out[n] = relu( dis[n] * (sum_{s in N(n)} h_scaled[s] + h_scaled[n]) + b )
__global__ __launch_bounds__(256) void agg_kernel(const __hip_bfloat16* __restrict__ h,
                                                  const float* __restrict__ dis,
                                                  const int* __restrict__ row_start,
                                                  const int* __restrict__ csr_src,
                                                  const float* __restrict__ bias,
                                                  float* __restrict__ out, int n) {
    int node = blockIdx.x * 4 + (threadIdx.x >> 6);   // one wave64 per node
    if (node >= n) return;
    int lane = threadIdx.x & 63;
    const __hip_bfloat162* hp = (const __hip_bfloat162*)h;   // 64 bf162 per row
    float dn = dis[node];
    float2 acc = __bfloat1622float2(hp[(size_t)node * 64 + lane]);  // self term (pre-scaled)
    int i0 = row_start[node], i1 = row_start[node + 1];
    for (int i = i0; i < i1; i++) {
        int s = csr_src[i];
        float2 v = __bfloat1622float2(hp[(size_t)s * 64 + lane]);
        acc.x += v.x;
        acc.y += v.y;
    }
    float2 bb = ((const float2*)bias)[lane];
    acc.x = fmaxf(fmaf(acc.x, dn, bb.x), 0.f);
    acc.y = fmaxf(fmaf(acc.y, dn, bb.y), 0.f);
    ((float2*)out)[(size_t)node * 64 + lane] = acc;
}

// ---------------- pooling: psum[g][f] += sum of h rows in graph g (batch sorted) ----------------
#define POOL_CHUNK 256
__global__ __launch_bounds__(128) void pool_kernel(const float* __restrict__ h,
                                                   const int* __restrict__ batch,
                                                   float* __restrict__ psum, int n) {
    int tid = threadIdx.x;   // feature
    int r0 = blockIdx.x * POOL_CHUNK;
    if (r0 >= n) return;
    int r1 = min(n, r0 + POOL_CHUNK);
    int cur = batch[r0];
    float acc = 0.f;
    for (int r = r0; r < r1; r++) {
        int g = batch[r];
        if (g != cur) {
            atomicAdd(&psum[cur * 128 + tid], acc);
            acc = 0.f;
            cur = g;
        }
        acc += h[(size_t)r * 128 + tid];
    }
    atomicAdd(&psum[cur * 128 + tid], acc);
}

// ---------------- fused final MLP: one block per graph ----------------
__global__ __launch_bounds__(256) void mlp_kernel(const float* __restrict__ psum,
                                                  const int* __restrict__ gstart,
                                                  const float* __restrict__ sv,
                                                  const float* __restrict__ act,
                                                  const float* __restrict__ Wf1,
                                                  const float* __restrict__ bf1,
                                                  const float* __restrict__ Wf2,
                                                  const float* __restrict__ bf2,
                                                  const float* __restrict__ Wo,
                                                  const float* __restrict__ bo,
                                                  float* __restrict__ out) {
    int g = blockIdx.x, tid = threadIdx.x;
    __shared__ float z[224];
    __shared__ float z1[256];
    __shared__ float red[256];
    if (tid < 128) {
        int c = gstart[g + 1] - gstart[g];
        float cnt = fmaxf((float)c, 1.f);
        z[tid] = psum[g * 128 + tid] / cnt;
    } else if (tid < 192) {
        z[tid] = sv[g * 64 + (tid - 128)];
    } else if (tid < 224) {
        z[tid] = act[g * 32 + (tid - 192)];
    }
    __syncthreads();
    float a = bf1[tid];
    for (int k = 0; k < 224; k++) a = fmaf(z[k], Wf1[k * 256 + tid], a);
    z1[tid] = fmaxf(a, 0.f);
    __syncthreads();
    float b = bf2[tid];
    for (int k = 0; k < 256; k++) b = fmaf(z1[k], Wf2[k * 256 + tid], b);
    b = fmaxf(b, 0.f);
    red[tid] = b * Wo[tid];
    __syncthreads();
    for (int off = 128; off > 0; off >>= 1) {
        if (tid < off) red[tid] += red[tid + off];
        __syncthreads();
    }
    if (tid == 0) out[g] = red[0] + bo[0];
}

// ---------------- launch ----------------
extern "C" void kernel_launch(void* const* d_in, const int* in_sizes, int n_in,
                              void* d_out, int out_size, void* d_ws, size_t ws_size,
                              hipStream_t stream) {
    const float* x   = (const float*)d_in[0];
    const int*   eidx = (const int*)d_in[1];
    const int*   batch = (const int*)d_in[2];
    const float* sv  = (const float*)d_in[3];
    const float* act = (const float*)d_in[4];
    const float* W1  = (const float*)d_in[5];
    const float* b1  = (const float*)d_in[6];
    const float* W2  = (const float*)d_in[7];
    const float* b2  = (const float*)d_in[8];
    const float* Wf1 = (const float*)d_in[9];
    const float* bf1 = (const float*)d_in[10];
    const float* Wf2 = (const float*)d_in[11];
    const float* bf2 = (const float*)d_in[12];
    const float* Wo  = (const float*)d_in[13];
    const float* bo  = (const float*)d_in[14];
    float* out = (float*)d_out;

    const int* srcp = eidx;             // edge_index[0]
    const int* dstp = eidx + N_EDGES;   // edge_index[1]

    char* w = (char*)d_ws;
    int* deg_cnt = (int*)w;            w += (size_t)N_NODES * 4;
    int* edge_pos = (int*)w;           w += (size_t)N_NODES * 4;
    float* psum = (float*)w;           w += (size_t)N_GRAPHS * HDIM * 4;
    int* row_start = (int*)w;          w += (size_t)(N_NODES + 1) * 4;
    float* dis = (float*)w;            w += (size_t)N_NODES * 4;
    int* gstart = (int*)w;             w += (size_t)(N_GRAPHS + 1) * 4;
    int* csr_src = (int*)w;            w += (size_t)N_EDGES * 4;
    w = (char*)(((uintptr_t)w + 255) & ~(uintptr_t)255);
    __hip_bfloat16* hbuf = (__hip_bfloat16*)w;  w += (size_t)N_NODES * HDIM * 2;
    w = (char*)(((uintptr_t)w + 255) & ~(uintptr_t)255);
    float* abuf = (float*)w;           w += (size_t)N_NODES * HDIM * 4;

    // zero deg_cnt + edge_pos + psum (contiguous)
    int zero_n = 2 * N_NODES + N_GRAPHS * HDIM;
    zero_kernel<<<(zero_n + 255) / 256, 256, 0, stream>>>(deg_cnt, zero_n);
    count_deg_kernel<<<(N_EDGES + 255) / 256, 256, 0, stream>>>(dstp, deg_cnt, N_EDGES);
    rsqrt_kernel<<<(N_NODES + 255) / 256, 256, 0, stream>>>(deg_cnt, dis, N_NODES);
    scan_kernel<<<1, 1024, 0, stream>>>(deg_cnt, row_start, N_NODES);
    fill_csr_kernel<<<(N_EDGES + 255) / 256, 256, 0, stream>>>(srcp, dstp, row_start, edge_pos, csr_src, N_EDGES);
    graph_bounds_kernel<<<(N_NODES + 255) / 256, 256, 0, stream>>>(batch, gstart, N_NODES, N_GRAPHS);

    int gemm_blocks = (N_NODES + 63) / 64;
    int agg_blocks = (N_NODES + 3) / 4;

    // conv1: h_scaled = (x @ W1) * dis ; agg+bias+relu -> abuf
    gemm_kernel<<<gemm_blocks, 256, 0, stream>>>(x, W1, dis, hbuf, N_NODES);
    agg_kernel<<<agg_blocks, 256, 0, stream>>>(hbuf, dis, row_start, csr_src, b1, abuf, N_NODES);
    // conv2
    gemm_kernel<<<gemm_blocks, 256, 0, stream>>>(abuf, W2, dis, hbuf, N_NODES);
    agg_kernel<<<agg_blocks, 256, 0, stream>>>(hbuf, dis, row_start, csr_src, b2, abuf, N_NODES);

    // pool + MLP
    pool_kernel<<<(N_NODES + POOL_CHUNK - 1) / POOL_CHUNK, 128, 0, stream>>>(abuf, batch, psum, N_NODES);
    mlp_kernel<<<N_GRAPHS, 256, 0, stream>>>(psum, gstart, sv, act, Wf1, bf1, Wf2, bf2, Wo, bo, out);
}

// Round 3
// 757.766 us; speedup vs baseline: 1.2641x; 1.2289x over previous
//
#include <hip/hip_runtime.h>
#include <hip/hip_bf16.h>
#include <stdint.h>

#define N_NODES 100000
#define N_EDGES 1600000
#define N_GRAPHS 64
#define HDIM 128
#define SCAN_BS 512
#define SCAN_NB ((N_NODES + SCAN_BS - 1) / SCAN_BS)   // 196

// ---------------- utility ----------------
__global__ void zero_kernel(int* __restrict__ p, int n) {
    int i = blockIdx.x * blockDim.x + threadIdx.x;
    if (i < n) p[i] = 0;
}

// ---------------- degree / CSR build ----------------
__global__ void count_deg_kernel(const int* __restrict__ dst, int* __restrict__ cnt, int E) {
    int e = blockIdx.x * blockDim.x + threadIdx.x;
    if (e < E) atomicAdd(&cnt[dst[e]], 1);
}

__global__ void rsqrt_kernel(const int* __restrict__ cnt, float* __restrict__ dis, int n) {
    int i = blockIdx.x * blockDim.x + threadIdx.x;
    if (i < n) dis[i] = rsqrtf((float)cnt[i] + 1.0f);
}

// ---------- 3-phase device-wide exclusive scan of cnt[0..n) -> row_start ----------
__global__ __launch_bounds__(SCAN_BS) void scan1_kernel(const int* __restrict__ cnt,
                                                        int* __restrict__ row_start,
                                                        int* __restrict__ bsum, int n) {
    __shared__ int s[SCAN_BS];
    int tid = threadIdx.x;
    int i = blockIdx.x * SCAN_BS + tid;
    int v = (i < n) ? cnt[i] : 0;
    s[tid] = v;
    __syncthreads();
#pragma unroll
    for (int off = 1; off < SCAN_BS; off <<= 1) {
        int t = (tid >= off) ? s[tid - off] : 0;
        __syncthreads();
        s[tid] += t;
        __syncthreads();
    }
    if (i < n) row_start[i] = s[tid] - v;          // local exclusive prefix
    if (tid == SCAN_BS - 1) bsum[blockIdx.x] = s[SCAN_BS - 1];
}

__global__ __launch_bounds__(256) void scan2_kernel(int* __restrict__ bsum,
                                                    int* __restrict__ row_start,
                                                    int nb, int n) {
    __shared__ int s[256];
    int tid = threadIdx.x;
    int v = (tid < nb) ? bsum[tid] : 0;
    s[tid] = v;
    __syncthreads();
#pragma unroll
    for (int off = 1; off < 256; off <<= 1) {
        int t = (tid >= off) ? s[tid - off] : 0;
        __syncthreads();
        s[tid] += t;
        __syncthreads();
    }
    if (tid < nb) bsum[tid] = s[tid] - v;          // exclusive block offsets
    if (tid == 255) row_start[n] = s[255];         // grand total
}

__global__ void scan3_kernel(int* __restrict__ row_start, const int* __restrict__ bsum, int n) {
    int i = blockIdx.x * blockDim.x + threadIdx.x;
    if (i < n) row_start[i] += bsum[i / SCAN_BS];
}

__global__ void fill_csr_kernel(const int* __restrict__ src, const int* __restrict__ dst,
                                const int* __restrict__ row_start, int* __restrict__ pos,
                                int* __restrict__ csr_src, int E) {
    int e = blockIdx.x * blockDim.x + threadIdx.x;
    if (e >= E) return;
    int d = dst[e];
    int p = row_start[d] + atomicAdd(&pos[d], 1);
    csr_src[p] = src[e];
}

// batch is sorted; gstart[g] = first node of graph g, gstart[G] = N
__global__ void graph_bounds_kernel(const int* __restrict__ batch, int* __restrict__ gstart,
                                    int n, int G) {
    int i = blockIdx.x * blockDim.x + threadIdx.x;
    if (i >= n) return;
    int b = batch[i];
    int prev = (i == 0) ? -1 : batch[i - 1];
    for (int g = prev + 1; g <= b; ++g) gstart[g] = i;
    if (i == n - 1) {
        for (int g = b + 1; g <= G; ++g) gstart[g] = n;
    }
}

// ---------------- GEMM: C[r][c] = (sum_k A[r][k] W[k][c]) * scale[r], bf16 output ----------------
__global__ __launch_bounds__(256) void gemm_kernel(const float* __restrict__ A,
                                                   const float* __restrict__ W,
                                                   const float* __restrict__ scale,
                                                   __hip_bfloat16* __restrict__ C, int nrows) {
    __shared__ float As[64][36];    // 64 rows x 32 k, pad to 36
    __shared__ float Ws[32][128];   // 32 k x 128 cols
    int tid = threadIdx.x;
    int row0 = blockIdx.x * 64;
    int tx = tid & 31;              // cols [tx*4, tx*4+4)
    int ty = tid >> 5;              // rows [ty*8, ty*8+8)
    float4 acc[8];
#pragma unroll
    for (int r = 0; r < 8; r++) acc[r] = make_float4(0.f, 0.f, 0.f, 0.f);

    for (int kt = 0; kt < 128; kt += 32) {
#pragma unroll
        for (int i = 0; i < 2; i++) {
            int f4 = tid + 256 * i;
            int r = f4 >> 3, c4 = f4 & 7;
            int grow = row0 + r;
            float4 v = make_float4(0.f, 0.f, 0.f, 0.f);
            if (grow < nrows) v = *(const float4*)(A + (size_t)grow * 128 + kt + c4 * 4);
            float* dp = &As[r][c4 * 4];
            dp[0] = v.x; dp[1] = v.y; dp[2] = v.z; dp[3] = v.w;
        }
#pragma unroll
        for (int i = 0; i < 4; i++) {
            int f4 = tid + 256 * i;
            int kr = f4 >> 5, c4 = f4 & 31;
            *(float4*)&Ws[kr][c4 * 4] = *(const float4*)(W + (size_t)(kt + kr) * 128 + c4 * 4);
        }
        __syncthreads();
#pragma unroll
        for (int k4 = 0; k4 < 32; k4 += 4) {
            float4 xv[8];
#pragma unroll
            for (int r = 0; r < 8; r++) xv[r] = *(const float4*)&As[ty * 8 + r][k4];
#pragma unroll
            for (int kk = 0; kk < 4; kk++) {
                float4 wv = *(const float4*)&Ws[k4 + kk][tx * 4];
#pragma unroll
                for (int r = 0; r < 8; r++) {
                    float xk = (&xv[r].x)[kk];
                    acc[r].x = fmaf(xk, wv.x, acc[r].x);
                    acc[r].y = fmaf(xk, wv.y, acc[r].y);
                    acc[r].z = fmaf(xk, wv.z, acc[r].z);
                    acc[r].w = fmaf(xk, wv.w, acc[r].w);
                }
            }
        }
        __syncthreads();
    }
#pragma unroll
    for (int r = 0; r < 8; r++) {
        int grow = row0 + ty * 8 + r;
        if (grow < nrows) {
            float s = scale[grow];
            __hip_bfloat162 p0 = __float22bfloat162_rn(make_float2(acc[r].x * s, acc[r].y * s));
            __hip_bfloat162 p1 = __float22bfloat162_rn(make_float2(acc[r].z * s, acc[r].w * s));
            uint2 pk;
            pk.x = *(unsigned int*)&p0;
            pk.y = *(unsigned int*)&p1;
            *(uint2*)(C + (size_t)grow * 128 + tx * 4) = pk;
        }
    }
}

// ---------------- GCN aggregation over pre-scaled bf16 h ----------------
__global__ __launch_bounds__(256) void agg_kernel(const __hip_bfloat16* __restrict__ h,
                                                  const float* __restrict__ dis,
                                                  const int* __restrict__ row_start,
                                                  const int* __restrict__ csr_src,
                                                  const float* __restrict__ bias,
                                                  float* __restrict__ out, int n) {
    int node = blockIdx.x * 4 + (threadIdx.x >> 6);   // one wave64 per node
    if (node >= n) return;
    int lane = threadIdx.x & 63;
    const __hip_bfloat162* hp = (const __hip_bfloat162*)h;   // 64 bf162 per row
    float dn = dis[node];
    float2 acc = __bfloat1622float2(hp[(size_t)node * 64 + lane]);  // self term (pre-scaled)
    int i0 = row_start[node], i1 = row_start[node + 1];
    for (int i = i0; i < i1; i++) {
        int s = csr_src[i];
        float2 v = __bfloat1622float2(hp[(size_t)s * 64 + lane]);
        acc.x += v.x;
        acc.y += v.y;
    }
    float2 bb = ((const float2*)bias)[lane];
    acc.x = fmaxf(fmaf(acc.x, dn, bb.x), 0.f);
    acc.y = fmaxf(fmaf(acc.y, dn, bb.y), 0.f);
    ((float2*)out)[(size_t)node * 64 + lane] = acc;
}

// ---------------- pooling ----------------
#define POOL_CHUNK 256
__global__ __launch_bounds__(128) void pool_kernel(const float* __restrict__ h,
                                                   const int* __restrict__ batch,
                                                   float* __restrict__ psum, int n) {
    int tid = threadIdx.x;   // feature
    int r0 = blockIdx.x * POOL_CHUNK;
    if (r0 >= n) return;
    int r1 = min(n, r0 + POOL_CHUNK);
    int cur = batch[r0];
    float acc = 0.f;
    for (int r = r0; r < r1; r++) {
        int g = batch[r];
        if (g != cur) {
            atomicAdd(&psum[cur * 128 + tid], acc);
            acc = 0.f;
            cur = g;
        }
        acc += h[(size_t)r * 128 + tid];
    }
    atomicAdd(&psum[cur * 128 + tid], acc);
}

// ---------------- fused final MLP: one block per graph ----------------
__global__ __launch_bounds__(256) void mlp_kernel(const float* __restrict__ psum,
                                                  const int* __restrict__ gstart,
                                                  const float* __restrict__ sv,
                                                  const float* __restrict__ act,
                                                  const float* __restrict__ Wf1,
                                                  const float* __restrict__ bf1,
                                                  const float* __restrict__ Wf2,
                                                  const float* __restrict__ bf2,
                                                  const float* __restrict__ Wo,
                                                  const float* __restrict__ bo,
                                                  float* __restrict__ out) {
    int g = blockIdx.x, tid = threadIdx.x;
    __shared__ float z[224];
    __shared__ float z1[256];
    __shared__ float red[256];
    if (tid < 128) {
        int c = gstart[g + 1] - gstart[g];
        float cnt = fmaxf((float)c, 1.f);
        z[tid] = psum[g * 128 + tid] / cnt;
    } else if (tid < 192) {
        z[tid] = sv[g * 64 + (tid - 128)];
    } else if (tid < 224) {
        z[tid] = act[g * 32 + (tid - 192)];
    }
    __syncthreads();
    float a = bf1[tid];
    for (int k = 0; k < 224; k++) a = fmaf(z[k], Wf1[k * 256 + tid], a);
    z1[tid] = fmaxf(a, 0.f);
    __syncthreads();
    float b = bf2[tid];
    for (int k = 0; k < 256; k++) b = fmaf(z1[k], Wf2[k * 256 + tid], b);
    b = fmaxf(b, 0.f);
    red[tid] = b * Wo[tid];
    __syncthreads();
    for (int off = 128; off > 0; off >>= 1) {
        if (tid < off) red[tid] += red[tid + off];
        __syncthreads();
    }
    if (tid == 0) out[g] = red[0] + bo[0];
}

// ---------------- launch ----------------
extern "C" void kernel_launch(void* const* d_in, const int* in_sizes, int n_in,
                              void* d_out, int out_size, void* d_ws, size_t ws_size,
                              hipStream_t stream) {
    const float* x   = (const float*)d_in[0];
    const int*   eidx = (const int*)d_in[1];
    const int*   batch = (const int*)d_in[2];
    const float* sv  = (const float*)d_in[3];
    const float* act = (const float*)d_in[4];
    const float* W1  = (const float*)d_in[5];
    const float* b1  = (const float*)d_in[6];
    const float* W2  = (const float*)d_in[7];
    const float* b2  = (const float*)d_in[8];
    const float* Wf1 = (const float*)d_in[9];
    const float* bf1 = (const float*)d_in[10];
    const float* Wf2 = (const float*)d_in[11];
    const float* bf2 = (const float*)d_in[12];
    const float* Wo  = (const float*)d_in[13];
    const float* bo  = (const float*)d_in[14];
    float* out = (float*)d_out;

    const int* srcp = eidx;             // edge_index[0]
    const int* dstp = eidx + N_EDGES;   // edge_index[1]

    char* w = (char*)d_ws;
    int* deg_cnt = (int*)w;            w += (size_t)N_NODES * 4;
    int* edge_pos = (int*)w;           w += (size_t)N_NODES * 4;
    float* psum = (float*)w;           w += (size_t)N_GRAPHS * HDIM * 4;
    int* row_start = (int*)w;          w += (size_t)(N_NODES + 1) * 4;
    float* dis = (float*)w;            w += (size_t)N_NODES * 4;
    int* gstart = (int*)w;             w += (size_t)(N_GRAPHS + 1) * 4;
    int* bsum = (int*)w;               w += (size_t)SCAN_NB * 4;
    int* csr_src = (int*)w;            w += (size_t)N_EDGES * 4;
    w = (char*)(((uintptr_t)w + 255) & ~(uintptr_t)255);
    __hip_bfloat16* hbuf = (__hip_bfloat16*)w;  w += (size_t)N_NODES * HDIM * 2;
    w = (char*)(((uintptr_t)w + 255) & ~(uintptr_t)255);
    float* abuf = (float*)w;           w += (size_t)N_NODES * HDIM * 4;

    // zero deg_cnt + edge_pos + psum (contiguous)
    int zero_n = 2 * N_NODES + N_GRAPHS * HDIM;
    zero_kernel<<<(zero_n + 255) / 256, 256, 0, stream>>>(deg_cnt, zero_n);
    count_deg_kernel<<<(N_EDGES + 255) / 256, 256, 0, stream>>>(dstp, deg_cnt, N_EDGES);
    rsqrt_kernel<<<(N_NODES + 255) / 256, 256, 0, stream>>>(deg_cnt, dis, N_NODES);
    scan1_kernel<<<SCAN_NB, SCAN_BS, 0, stream>>>(deg_cnt, row_start, bsum, N_NODES);
    scan2_kernel<<<1, 256, 0, stream>>>(bsum, row_start, SCAN_NB, N_NODES);
    scan3_kernel<<<(N_NODES + 255) / 256, 256, 0, stream>>>(row_start, bsum, N_NODES);
    fill_csr_kernel<<<(N_EDGES + 255) / 256, 256, 0, stream>>>(srcp, dstp, row_start, edge_pos, csr_src, N_EDGES);
    graph_bounds_kernel<<<(N_NODES + 255) / 256, 256, 0, stream>>>(batch, gstart, N_NODES, N_GRAPHS);

    int gemm_blocks = (N_NODES + 63) / 64;
    int agg_blocks = (N_NODES + 3) / 4;

    // conv1: h_scaled = (x @ W1) * dis ; agg+bias+relu -> abuf
    gemm_kernel<<<gemm_blocks, 256, 0, stream>>>(x, W1, dis, hbuf, N_NODES);
    agg_kernel<<<agg_blocks, 256, 0, stream>>>(hbuf, dis, row_start, csr_src, b1, abuf, N_NODES);
    // conv2
    gemm_kernel<<<gemm_blocks, 256, 0, stream>>>(abuf, W2, dis, hbuf, N_NODES);
    agg_kernel<<<agg_blocks, 256, 0, stream>>>(hbuf, dis, row_start, csr_src, b2, abuf, N_NODES);

    // pool + MLP
    pool_kernel<<<(N_NODES + POOL_CHUNK - 1) / POOL_CHUNK, 128, 0, stream>>>(abuf, batch, psum, N_NODES);
    mlp_kernel<<<N_GRAPHS, 256, 0, stream>>>(psum, gstart, sv, act, Wf1, bf1, Wf2, bf2, Wo, bo, out);
}

// Round 4
// 619.667 us; speedup vs baseline: 1.5458x; 1.2229x over previous
//
#include <hip/hip_runtime.h>
#include <hip/hip_bf16.h>
#include <stdint.h>

#define N_NODES 100000
#define N_EDGES 1600000
#define N_GRAPHS 64
#define HDIM 128
#define SCAN_BS 512
#define SCAN_NB ((N_NODES + SCAN_BS - 1) / SCAN_BS)   // 196

// ---------------- utility ----------------
__global__ void zero_kernel(int* __restrict__ p, int n) {
    int i = blockIdx.x * blockDim.x + threadIdx.x;
    if (i < n) p[i] = 0;
}

// fp32 -> bf16, 8 elements per thread
__global__ void cvt_bf16_kernel(const float* __restrict__ a, __hip_bfloat16* __restrict__ o, int n8) {
    int i = blockIdx.x * blockDim.x + threadIdx.x;
    if (i >= n8) return;
    const float4* ap = (const float4*)a;
    float4 v0 = ap[i * 2], v1 = ap[i * 2 + 1];
    __hip_bfloat162 p0 = __float22bfloat162_rn(make_float2(v0.x, v0.y));
    __hip_bfloat162 p1 = __float22bfloat162_rn(make_float2(v0.z, v0.w));
    __hip_bfloat162 p2 = __float22bfloat162_rn(make_float2(v1.x, v1.y));
    __hip_bfloat162 p3 = __float22bfloat162_rn(make_float2(v1.z, v1.w));
    uint4 pk;
    pk.x = *(unsigned int*)&p0; pk.y = *(unsigned int*)&p1;
    pk.z = *(unsigned int*)&p2; pk.w = *(unsigned int*)&p3;
    ((uint4*)o)[i] = pk;
}

// ---------------- degree / CSR build ----------------
__global__ void count_deg_kernel(const int* __restrict__ dst, int* __restrict__ cnt, int E) {
    int e = blockIdx.x * blockDim.x + threadIdx.x;
    if (e < E) atomicAdd(&cnt[dst[e]], 1);
}

__global__ void rsqrt_kernel(const int* __restrict__ cnt, float* __restrict__ dis, int n) {
    int i = blockIdx.x * blockDim.x + threadIdx.x;
    if (i < n) dis[i] = rsqrtf((float)cnt[i] + 1.0f);
}

// ---------- 3-phase device-wide exclusive scan ----------
__global__ __launch_bounds__(SCAN_BS) void scan1_kernel(const int* __restrict__ cnt,
                                                        int* __restrict__ row_start,
                                                        int* __restrict__ bsum, int n) {
    __shared__ int s[SCAN_BS];
    int tid = threadIdx.x;
    int i = blockIdx.x * SCAN_BS + tid;
    int v = (i < n) ? cnt[i] : 0;
    s[tid] = v;
    __syncthreads();
#pragma unroll
    for (int off = 1; off < SCAN_BS; off <<= 1) {
        int t = (tid >= off) ? s[tid - off] : 0;
        __syncthreads();
        s[tid] += t;
        __syncthreads();
    }
    if (i < n) row_start[i] = s[tid] - v;
    if (tid == SCAN_BS - 1) bsum[blockIdx.x] = s[SCAN_BS - 1];
}

__global__ __launch_bounds__(256) void scan2_kernel(int* __restrict__ bsum,
                                                    int* __restrict__ row_start,
                                                    int nb, int n) {
    __shared__ int s[256];
    int tid = threadIdx.x;
    int v = (tid < nb) ? bsum[tid] : 0;
    s[tid] = v;
    __syncthreads();
#pragma unroll
    for (int off = 1; off < 256; off <<= 1) {
        int t = (tid >= off) ? s[tid - off] : 0;
        __syncthreads();
        s[tid] += t;
        __syncthreads();
    }
    if (tid < nb) bsum[tid] = s[tid] - v;
    if (tid == 255) row_start[n] = s[255];
}

__global__ void scan3_kernel(int* __restrict__ row_start, const int* __restrict__ bsum, int n) {
    int i = blockIdx.x * blockDim.x + threadIdx.x;
    if (i < n) row_start[i] += bsum[i / SCAN_BS];
}

__global__ void fill_csr_kernel(const int* __restrict__ src, const int* __restrict__ dst,
                                const int* __restrict__ row_start, int* __restrict__ pos,
                                int* __restrict__ csr_src, int E) {
    int e = blockIdx.x * blockDim.x + threadIdx.x;
    if (e >= E) return;
    int d = dst[e];
    int p = row_start[d] + atomicAdd(&pos[d], 1);
    csr_src[p] = src[e];
}

__global__ void graph_bounds_kernel(const int* __restrict__ batch, int* __restrict__ gstart,
                                    int n, int G) {
    int i = blockIdx.x * blockDim.x + threadIdx.x;
    if (i >= n) return;
    int b = batch[i];
    int prev = (i == 0) ? -1 : batch[i - 1];
    for (int g = prev + 1; g <= b; ++g) gstart[g] = i;
    if (i == n - 1) {
        for (int g = b + 1; g <= G; ++g) gstart[g] = n;
    }
}

// ---------------- GEMM: C[r][c] = (sum_k A[r][k] W[k][c]) * scale[r]
// A bf16 [nrows x 128], W fp32 [128 x 128], C bf16 (pre-scaled for next hop)
__global__ __launch_bounds__(256) void gemm_kernel(const __hip_bfloat16* __restrict__ A,
                                                   const float* __restrict__ W,
                                                   const float* __restrict__ scale,
                                                   __hip_bfloat16* __restrict__ C, int nrows) {
    __shared__ float As[64][36];    // 64 rows x 32 k, pad to 36
    __shared__ float Ws[32][128];   // 32 k x 128 cols
    int tid = threadIdx.x;
    int row0 = blockIdx.x * 64;
    int tx = tid & 31;              // cols [tx*4, tx*4+4)
    int ty = tid >> 5;              // rows [ty*8, ty*8+8)
    float4 acc[8];
#pragma unroll
    for (int r = 0; r < 8; r++) acc[r] = make_float4(0.f, 0.f, 0.f, 0.f);

    for (int kt = 0; kt < 128; kt += 32) {
        // A tile: 64x32 bf16 = 256 x (8 bf16), 1 uint4 per thread
        {
            int r = tid >> 2, c8 = (tid & 3) * 8;
            int grow = row0 + r;
            uint4 u = make_uint4(0, 0, 0, 0);
            if (grow < nrows) u = *(const uint4*)(A + (size_t)grow * 128 + kt + c8);
            float2 f0 = __bfloat1622float2(*(__hip_bfloat162*)&u.x);
            float2 f1 = __bfloat1622float2(*(__hip_bfloat162*)&u.y);
            float2 f2 = __bfloat1622float2(*(__hip_bfloat162*)&u.z);
            float2 f3 = __bfloat1622float2(*(__hip_bfloat162*)&u.w);
            float* dp = &As[r][c8];
            *(float4*)dp = make_float4(f0.x, f0.y, f1.x, f1.y);
            *(float4*)(dp + 4) = make_float4(f2.x, f2.y, f3.x, f3.y);
        }
        // W tile: 32x128 floats = 1024 float4, 4 per thread
#pragma unroll
        for (int i = 0; i < 4; i++) {
            int f4 = tid + 256 * i;
            int kr = f4 >> 5, c4 = f4 & 31;
            *(float4*)&Ws[kr][c4 * 4] = *(const float4*)(W + (size_t)(kt + kr) * 128 + c4 * 4);
        }
        __syncthreads();
#pragma unroll
        for (int k4 = 0; k4 < 32; k4 += 4) {
            float4 xv[8];
#pragma unroll
            for (int r = 0; r < 8; r++) xv[r] = *(const float4*)&As[ty * 8 + r][k4];
#pragma unroll
            for (int kk = 0; kk < 4; kk++) {
                float4 wv = *(const float4*)&Ws[k4 + kk][tx * 4];
#pragma unroll
                for (int r = 0; r < 8; r++) {
                    float xk = (&xv[r].x)[kk];
                    acc[r].x = fmaf(xk, wv.x, acc[r].x);
                    acc[r].y = fmaf(xk, wv.y, acc[r].y);
                    acc[r].z = fmaf(xk, wv.z, acc[r].z);
                    acc[r].w = fmaf(xk, wv.w, acc[r].w);
                }
            }
        }
        __syncthreads();
    }
#pragma unroll
    for (int r = 0; r < 8; r++) {
        int grow = row0 + ty * 8 + r;
        if (grow < nrows) {
            float s = scale[grow];
            __hip_bfloat162 p0 = __float22bfloat162_rn(make_float2(acc[r].x * s, acc[r].y * s));
            __hip_bfloat162 p1 = __float22bfloat162_rn(make_float2(acc[r].z * s, acc[r].w * s));
            uint2 pk;
            pk.x = *(unsigned int*)&p0;
            pk.y = *(unsigned int*)&p1;
            *(uint2*)(C + (size_t)grow * 128 + tx * 4) = pk;
        }
    }
}

// ---------------- GCN aggregation over pre-scaled bf16 h, bf16 out ----------------
// out[n] = bf16( relu( dis[n] * (sum_{s in N(n)} h[s] + h[n]) + b ) )
__global__ __launch_bounds__(256) void agg_kernel(const __hip_bfloat16* __restrict__ h,
                                                  const float* __restrict__ dis,
                                                  const int* __restrict__ row_start,
                                                  const int* __restrict__ csr_src,
                                                  const float* __restrict__ bias,
                                                  __hip_bfloat16* __restrict__ out, int n) {
    int node = blockIdx.x * 4 + (threadIdx.x >> 6);   // one wave64 per node
    if (node >= n) return;
    int lane = threadIdx.x & 63;
    const __hip_bfloat162* hp = (const __hip_bfloat162*)h;   // 64 bf162 per row
    float dn = dis[node];
    float2 acc = __bfloat1622float2(hp[(size_t)node * 64 + lane]);  // self (pre-scaled)
    int i0 = row_start[node], i1 = row_start[node + 1];
    int i = i0;
    // unroll by 8: 8 independent row gathers in flight per wave
    for (; i + 8 <= i1; i += 8) {
        int s0 = csr_src[i + 0], s1 = csr_src[i + 1];
        int s2 = csr_src[i + 2], s3 = csr_src[i + 3];
        int s4 = csr_src[i + 4], s5 = csr_src[i + 5];
        int s6 = csr_src[i + 6], s7 = csr_src[i + 7];
        float2 v0 = __bfloat1622float2(hp[(size_t)s0 * 64 + lane]);
        float2 v1 = __bfloat1622float2(hp[(size_t)s1 * 64 + lane]);
        float2 v2 = __bfloat1622float2(hp[(size_t)s2 * 64 + lane]);
        float2 v3 = __bfloat1622float2(hp[(size_t)s3 * 64 + lane]);
        float2 v4 = __bfloat1622float2(hp[(size_t)s4 * 64 + lane]);
        float2 v5 = __bfloat1622float2(hp[(size_t)s5 * 64 + lane]);
        float2 v6 = __bfloat1622float2(hp[(size_t)s6 * 64 + lane]);
        float2 v7 = __bfloat1622float2(hp[(size_t)s7 * 64 + lane]);
        acc.x += ((v0.x + v1.x) + (v2.x + v3.x)) + ((v4.x + v5.x) + (v6.x + v7.x));
        acc.y += ((v0.y + v1.y) + (v2.y + v3.y)) + ((v4.y + v5.y) + (v6.y + v7.y));
    }
    for (; i < i1; i++) {
        int s = csr_src[i];
        float2 v = __bfloat1622float2(hp[(size_t)s * 64 + lane]);
        acc.x += v.x;
        acc.y += v.y;
    }
    float2 bb = ((const float2*)bias)[lane];
    acc.x = fmaxf(fmaf(acc.x, dn, bb.x), 0.f);
    acc.y = fmaxf(fmaf(acc.y, dn, bb.y), 0.f);
    __hip_bfloat162 pk = __float22bfloat162_rn(acc);
    ((__hip_bfloat162*)out)[(size_t)node * 64 + lane] = pk;
}

// ---------------- pooling over bf16 h ----------------
#define POOL_CHUNK 256
__global__ __launch_bounds__(128) void pool_kernel(const __hip_bfloat16* __restrict__ h,
                                                   const int* __restrict__ batch,
                                                   float* __restrict__ psum, int n) {
    int tid = threadIdx.x;   // feature
    int r0 = blockIdx.x * POOL_CHUNK;
    if (r0 >= n) return;
    int r1 = min(n, r0 + POOL_CHUNK);
    int cur = batch[r0];
    float acc = 0.f;
    for (int r = r0; r < r1; r++) {
        int g = batch[r];
        if (g != cur) {
            atomicAdd(&psum[cur * 128 + tid], acc);
            acc = 0.f;
            cur = g;
        }
        acc += __bfloat162float(h[(size_t)r * 128 + tid]);
    }
    atomicAdd(&psum[cur * 128 + tid], acc);
}

// ---------------- fused final MLP: one block per graph ----------------
__global__ __launch_bounds__(256) void mlp_kernel(const float* __restrict__ psum,
                                                  const int* __restrict__ gstart,
                                                  const float* __restrict__ sv,
                                                  const float* __restrict__ act,
                                                  const float* __restrict__ Wf1,
                                                  const float* __restrict__ bf1,
                                                  const float* __restrict__ Wf2,
                                                  const float* __restrict__ bf2,
                                                  const float* __restrict__ Wo,
                                                  const float* __restrict__ bo,
                                                  float* __restrict__ out) {
    int g = blockIdx.x, tid = threadIdx.x;
    __shared__ float z[224];
    __shared__ float z1[256];
    __shared__ float red[256];
    if (tid < 128) {
        int c = gstart[g + 1] - gstart[g];
        float cnt = fmaxf((float)c, 1.f);
        z[tid] = psum[g * 128 + tid] / cnt;
    } else if (tid < 192) {
        z[tid] = sv[g * 64 + (tid - 128)];
    } else if (tid < 224) {
        z[tid] = act[g * 32 + (tid - 192)];
    }
    __syncthreads();
    float a = bf1[tid];
    for (int k = 0; k < 224; k++) a = fmaf(z[k], Wf1[k * 256 + tid], a);
    z1[tid] = fmaxf(a, 0.f);
    __syncthreads();
    float b = bf2[tid];
    for (int k = 0; k < 256; k++) b = fmaf(z1[k], Wf2[k * 256 + tid], b);
    b = fmaxf(b, 0.f);
    red[tid] = b * Wo[tid];
    __syncthreads();
    for (int off = 128; off > 0; off >>= 1) {
        if (tid < off) red[tid] += red[tid + off];
        __syncthreads();
    }
    if (tid == 0) out[g] = red[0] + bo[0];
}

// ---------------- launch ----------------
extern "C" void kernel_launch(void* const* d_in, const int* in_sizes, int n_in,
                              void* d_out, int out_size, void* d_ws, size_t ws_size,
                              hipStream_t stream) {
    const float* x   = (const float*)d_in[0];
    const int*   eidx = (const int*)d_in[1];
    const int*   batch = (const int*)d_in[2];
    const float* sv  = (const float*)d_in[3];
    const float* act = (const float*)d_in[4];
    const float* W1  = (const float*)d_in[5];
    const float* b1  = (const float*)d_in[6];
    const float* W2  = (const float*)d_in[7];
    const float* b2  = (const float*)d_in[8];
    const float* Wf1 = (const float*)d_in[9];
    const float* bf1 = (const float*)d_in[10];
    const float* Wf2 = (const float*)d_in[11];
    const float* bf2 = (const float*)d_in[12];
    const float* Wo  = (const float*)d_in[13];
    const float* bo  = (const float*)d_in[14];
    float* out = (float*)d_out;

    const int* srcp = eidx;             // edge_index[0]
    const int* dstp = eidx + N_EDGES;   // edge_index[1]

    char* w = (char*)d_ws;
    int* deg_cnt = (int*)w;            w += (size_t)N_NODES * 4;
    int* edge_pos = (int*)w;           w += (size_t)N_NODES * 4;
    float* psum = (float*)w;           w += (size_t)N_GRAPHS * HDIM * 4;
    int* row_start = (int*)w;          w += (size_t)(N_NODES + 1) * 4;
    float* dis = (float*)w;            w += (size_t)N_NODES * 4;
    int* gstart = (int*)w;             w += (size_t)(N_GRAPHS + 1) * 4;
    int* bsum = (int*)w;               w += (size_t)SCAN_NB * 4;
    int* csr_src = (int*)w;            w += (size_t)N_EDGES * 4;
    w = (char*)(((uintptr_t)w + 255) & ~(uintptr_t)255);
    __hip_bfloat16* xb = (__hip_bfloat16*)w;    w += (size_t)N_NODES * HDIM * 2;
    __hip_bfloat16* hbuf = (__hip_bfloat16*)w;  w += (size_t)N_NODES * HDIM * 2;
    __hip_bfloat16* abuf = (__hip_bfloat16*)w;  w += (size_t)N_NODES * HDIM * 2;

    // zero deg_cnt + edge_pos + psum (contiguous)
    int zero_n = 2 * N_NODES + N_GRAPHS * HDIM;
    zero_kernel<<<(zero_n + 255) / 256, 256, 0, stream>>>(deg_cnt, zero_n);
    cvt_bf16_kernel<<<(N_NODES * HDIM / 8 + 255) / 256, 256, 0, stream>>>(x, xb, N_NODES * HDIM / 8);
    count_deg_kernel<<<(N_EDGES + 255) / 256, 256, 0, stream>>>(dstp, deg_cnt, N_EDGES);
    rsqrt_kernel<<<(N_NODES + 255) / 256, 256, 0, stream>>>(deg_cnt, dis, N_NODES);
    scan1_kernel<<<SCAN_NB, SCAN_BS, 0, stream>>>(deg_cnt, row_start, bsum, N_NODES);
    scan2_kernel<<<1, 256, 0, stream>>>(bsum, row_start, SCAN_NB, N_NODES);
    scan3_kernel<<<(N_NODES + 255) / 256, 256, 0, stream>>>(row_start, bsum, N_NODES);
    fill_csr_kernel<<<(N_EDGES + 255) / 256, 256, 0, stream>>>(srcp, dstp, row_start, edge_pos, csr_src, N_EDGES);
    graph_bounds_kernel<<<(N_NODES + 255) / 256, 256, 0, stream>>>(batch, gstart, N_NODES, N_GRAPHS);

    int gemm_blocks = (N_NODES + 63) / 64;
    int agg_blocks = (N_NODES + 3) / 4;

    // conv1: h_scaled = (xb @ W1) * dis ; agg+bias+relu -> abuf (bf16)
    gemm_kernel<<<gemm_blocks, 256, 0, stream>>>(xb, W1, dis, hbuf, N_NODES);
    agg_kernel<<<agg_blocks, 256, 0, stream>>>(hbuf, dis, row_start, csr_src, b1, abuf, N_NODES);
    // conv2
    gemm_kernel<<<gemm_blocks, 256, 0, stream>>>(abuf, W2, dis, hbuf, N_NODES);
    agg_kernel<<<agg_blocks, 256, 0, stream>>>(hbuf, dis, row_start, csr_src, b2, abuf, N_NODES);

    // pool + MLP
    pool_kernel<<<(N_NODES + POOL_CHUNK - 1) / POOL_CHUNK, 128, 0, stream>>>(abuf, batch, psum, N_NODES);
    mlp_kernel<<<N_GRAPHS, 256, 0, stream>>>(psum, gstart, sv, act, Wf1, bf1, Wf2, bf2, Wo, bo, out);
}

// Round 5
// 520.425 us; speedup vs baseline: 1.8406x; 1.1907x over previous
//
#include <hip/hip_runtime.h>
#include <hip/hip_bf16.h>
#include <stdint.h>

#define N_NODES 100000
#define N_EDGES 1600000
#define N_GRAPHS 64
#define HDIM 128
#define SCAN_BS 512
#define SCAN_NB ((N_NODES + SCAN_BS - 1) / SCAN_BS)   // 196

#define BUCKET_SHIFT 9
#define NBUCK ((N_NODES + 511) >> 9)                  // 196
#define SCAT_CHUNK 4096
#define SCAT_NBLK ((N_EDGES + SCAT_CHUNK - 1) / SCAT_CHUNK)  // 391

// ---------------- utility ----------------
__global__ void zero_kernel(int* __restrict__ p, int n) {
    int i = blockIdx.x * blockDim.x + threadIdx.x;
    if (i < n) p[i] = 0;
}

// fp32 -> bf16, 8 elements per thread
__global__ void cvt_bf16_kernel(const float* __restrict__ a, __hip_bfloat16* __restrict__ o, int n8) {
    int i = blockIdx.x * blockDim.x + threadIdx.x;
    if (i >= n8) return;
    const float4* ap = (const float4*)a;
    float4 v0 = ap[i * 2], v1 = ap[i * 2 + 1];
    __hip_bfloat162 p0 = __float22bfloat162_rn(make_float2(v0.x, v0.y));
    __hip_bfloat162 p1 = __float22bfloat162_rn(make_float2(v0.z, v0.w));
    __hip_bfloat162 p2 = __float22bfloat162_rn(make_float2(v1.x, v1.y));
    __hip_bfloat162 p3 = __float22bfloat162_rn(make_float2(v1.z, v1.w));
    uint4 pk;
    pk.x = *(unsigned int*)&p0; pk.y = *(unsigned int*)&p1;
    pk.z = *(unsigned int*)&p2; pk.w = *(unsigned int*)&p3;
    ((uint4*)o)[i] = pk;
}

// ---------------- bucketed counting sort of edges by dst ----------------
// Phase A: global bucket histogram (LDS-aggregated)
__global__ __launch_bounds__(256) void hist_kernel(const int* __restrict__ dst,
                                                   int* __restrict__ bhist, int E) {
    __shared__ int hist[NBUCK];
    int tid = threadIdx.x;
    if (tid < NBUCK) hist[tid] = 0;
    __syncthreads();
    int e0 = blockIdx.x * SCAT_CHUNK;
#pragma unroll
    for (int j = 0; j < SCAT_CHUNK / 256; j++) {
        int e = e0 + (j << 8) + tid;
        if (e < E) atomicAdd(&hist[dst[e] >> BUCKET_SHIFT], 1);
    }
    __syncthreads();
    if (tid < NBUCK && hist[tid] > 0) atomicAdd(&bhist[tid], hist[tid]);
}

// Phase B: scan bucket histogram -> bucket_base, init gcur
__global__ __launch_bounds__(256) void bucket_scan_kernel(const int* __restrict__ bhist,
                                                          int* __restrict__ bucket_base,
                                                          int* __restrict__ gcur) {
    __shared__ int s[256];
    int tid = threadIdx.x;
    int v = (tid < NBUCK) ? bhist[tid] : 0;
    s[tid] = v;
    __syncthreads();
#pragma unroll
    for (int off = 1; off < 256; off <<= 1) {
        int t = (tid >= off) ? s[tid - off] : 0;
        __syncthreads();
        s[tid] += t;
        __syncthreads();
    }
    if (tid < NBUCK) {
        int excl = s[tid] - v;
        bucket_base[tid] = excl;
        gcur[tid] = excl;
    }
}

// Phase C: scatter edges into bucket-sorted order (int2 = {src, dst})
__global__ __launch_bounds__(256) void scatter_kernel(const int* __restrict__ src,
                                                      const int* __restrict__ dst,
                                                      int* __restrict__ gcur,
                                                      int2* __restrict__ sorted, int E) {
    __shared__ int hist[NBUCK];
    __shared__ int base_s[NBUCK];
    int tid = threadIdx.x;
    int e0 = blockIdx.x * SCAT_CHUNK;
    int sv[SCAT_CHUNK / 256], dv[SCAT_CHUNK / 256];
#pragma unroll
    for (int j = 0; j < SCAT_CHUNK / 256; j++) {
        int e = e0 + (j << 8) + tid;
        if (e < E) { sv[j] = src[e]; dv[j] = dst[e]; } else { sv[j] = -1; dv[j] = -1; }
    }
    if (tid < NBUCK) hist[tid] = 0;
    __syncthreads();
#pragma unroll
    for (int j = 0; j < SCAT_CHUNK / 256; j++)
        if (dv[j] >= 0) atomicAdd(&hist[dv[j] >> BUCKET_SHIFT], 1);
    __syncthreads();
    if (tid < NBUCK) {
        int c = hist[tid];
        base_s[tid] = (c > 0) ? atomicAdd(&gcur[tid], c) : 0;
    }
    __syncthreads();
    if (tid < NBUCK) hist[tid] = 0;
    __syncthreads();
#pragma unroll
    for (int j = 0; j < SCAT_CHUNK / 256; j++) {
        if (dv[j] >= 0) {
            int b = dv[j] >> BUCKET_SHIFT;
            int idx = atomicAdd(&hist[b], 1);
            sorted[base_s[b] + idx] = make_int2(sv[j], dv[j]);
        }
    }
}

// Phase C2: per-bucket degree count (coalesced deg + dis writes)
__global__ __launch_bounds__(256) void deg_bucket_kernel(const int2* __restrict__ sorted,
                                                         const int* __restrict__ bucket_base,
                                                         const int* __restrict__ gcur,
                                                         int* __restrict__ deg_cnt,
                                                         float* __restrict__ dis) {
    __shared__ int cnt[512];
    int b = blockIdx.x, tid = threadIdx.x;
    cnt[tid] = 0; cnt[tid + 256] = 0;
    __syncthreads();
    int node0 = b << BUCKET_SHIFT;
    int lo = bucket_base[b], hi = gcur[b];
    for (int i = lo + tid; i < hi; i += 256)
        atomicAdd(&cnt[sorted[i].y - node0], 1);
    __syncthreads();
#pragma unroll
    for (int k = 0; k < 2; k++) {
        int li = tid + k * 256;
        int node = node0 + li;
        if (node < N_NODES) {
            int c = cnt[li];
            deg_cnt[node] = c;
            dis[node] = rsqrtf((float)c + 1.0f);
        }
    }
}

// Phase D: per-bucket CSR fill (writes confined to bucket's csr slice)
__global__ __launch_bounds__(256) void fill_bucket_kernel(const int2* __restrict__ sorted,
                                                          const int* __restrict__ bucket_base,
                                                          const int* __restrict__ gcur,
                                                          const int* __restrict__ row_start,
                                                          int* __restrict__ csr_src) {
    __shared__ int posl[512];
    int b = blockIdx.x, tid = threadIdx.x;
    posl[tid] = 0; posl[tid + 256] = 0;
    __syncthreads();
    int node0 = b << BUCKET_SHIFT;
    int lo = bucket_base[b], hi = gcur[b];
    for (int i = lo + tid; i < hi; i += 256) {
        int2 e = sorted[i];
        int idx = atomicAdd(&posl[e.y - node0], 1);
        csr_src[row_start[e.y] + idx] = e.x;
    }
}

// ---------- 3-phase device-wide exclusive scan ----------
__global__ __launch_bounds__(SCAN_BS) void scan1_kernel(const int* __restrict__ cnt,
                                                        int* __restrict__ row_start,
                                                        int* __restrict__ bsum, int n) {
    __shared__ int s[SCAN_BS];
    int tid = threadIdx.x;
    int i = blockIdx.x * SCAN_BS + tid;
    int v = (i < n) ? cnt[i] : 0;
    s[tid] = v;
    __syncthreads();
#pragma unroll
    for (int off = 1; off < SCAN_BS; off <<= 1) {
        int t = (tid >= off) ? s[tid - off] : 0;
        __syncthreads();
        s[tid] += t;
        __syncthreads();
    }
    if (i < n) row_start[i] = s[tid] - v;
    if (tid == SCAN_BS - 1) bsum[blockIdx.x] = s[SCAN_BS - 1];
}

__global__ __launch_bounds__(256) void scan2_kernel(int* __restrict__ bsum,
                                                    int* __restrict__ row_start,
                                                    int nb, int n) {
    __shared__ int s[256];
    int tid = threadIdx.x;
    int v = (tid < nb) ? bsum[tid] : 0;
    s[tid] = v;
    __syncthreads();
#pragma unroll
    for (int off = 1; off < 256; off <<= 1) {
        int t = (tid >= off) ? s[tid - off] : 0;
        __syncthreads();
        s[tid] += t;
        __syncthreads();
    }
    if (tid < nb) bsum[tid] = s[tid] - v;
    if (tid == 255) row_start[n] = s[255];
}

__global__ void scan3_kernel(int* __restrict__ row_start, const int* __restrict__ bsum, int n) {
    int i = blockIdx.x * blockDim.x + threadIdx.x;
    if (i < n) row_start[i] += bsum[i / SCAN_BS];
}

__global__ void graph_bounds_kernel(const int* __restrict__ batch, int* __restrict__ gstart,
                                    int n, int G) {
    int i = blockIdx.x * blockDim.x + threadIdx.x;
    if (i >= n) return;
    int b = batch[i];
    int prev = (i == 0) ? -1 : batch[i - 1];
    for (int g = prev + 1; g <= b; ++g) gstart[g] = i;
    if (i == n - 1) {
        for (int g = b + 1; g <= G; ++g) gstart[g] = n;
    }
}

// ---------------- GEMM: C[r][c] = (sum_k A[r][k] W[k][c]) * scale[r]
__global__ __launch_bounds__(256) void gemm_kernel(const __hip_bfloat16* __restrict__ A,
                                                   const float* __restrict__ W,
                                                   const float* __restrict__ scale,
                                                   __hip_bfloat16* __restrict__ C, int nrows) {
    __shared__ float As[64][36];
    __shared__ float Ws[32][128];
    int tid = threadIdx.x;
    int row0 = blockIdx.x * 64;
    int tx = tid & 31;
    int ty = tid >> 5;
    float4 acc[8];
#pragma unroll
    for (int r = 0; r < 8; r++) acc[r] = make_float4(0.f, 0.f, 0.f, 0.f);

    for (int kt = 0; kt < 128; kt += 32) {
        {
            int r = tid >> 2, c8 = (tid & 3) * 8;
            int grow = row0 + r;
            uint4 u = make_uint4(0, 0, 0, 0);
            if (grow < nrows) u = *(const uint4*)(A + (size_t)grow * 128 + kt + c8);
            float2 f0 = __bfloat1622float2(*(__hip_bfloat162*)&u.x);
            float2 f1 = __bfloat1622float2(*(__hip_bfloat162*)&u.y);
            float2 f2 = __bfloat1622float2(*(__hip_bfloat162*)&u.z);
            float2 f3 = __bfloat1622float2(*(__hip_bfloat162*)&u.w);
            float* dp = &As[r][c8];
            *(float4*)dp = make_float4(f0.x, f0.y, f1.x, f1.y);
            *(float4*)(dp + 4) = make_float4(f2.x, f2.y, f3.x, f3.y);
        }
#pragma unroll
        for (int i = 0; i < 4; i++) {
            int f4 = tid + 256 * i;
            int kr = f4 >> 5, c4 = f4 & 31;
            *(float4*)&Ws[kr][c4 * 4] = *(const float4*)(W + (size_t)(kt + kr) * 128 + c4 * 4);
        }
        __syncthreads();
#pragma unroll
        for (int k4 = 0; k4 < 32; k4 += 4) {
            float4 xv[8];
#pragma unroll
            for (int r = 0; r < 8; r++) xv[r] = *(const float4*)&As[ty * 8 + r][k4];
#pragma unroll
            for (int kk = 0; kk < 4; kk++) {
                float4 wv = *(const float4*)&Ws[k4 + kk][tx * 4];
#pragma unroll
                for (int r = 0; r < 8; r++) {
                    float xk = (&xv[r].x)[kk];
                    acc[r].x = fmaf(xk, wv.x, acc[r].x);
                    acc[r].y = fmaf(xk, wv.y, acc[r].y);
                    acc[r].z = fmaf(xk, wv.z, acc[r].z);
                    acc[r].w = fmaf(xk, wv.w, acc[r].w);
                }
            }
        }
        __syncthreads();
    }
#pragma unroll
    for (int r = 0; r < 8; r++) {
        int grow = row0 + ty * 8 + r;
        if (grow < nrows) {
            float s = scale[grow];
            __hip_bfloat162 p0 = __float22bfloat162_rn(make_float2(acc[r].x * s, acc[r].y * s));
            __hip_bfloat162 p1 = __float22bfloat162_rn(make_float2(acc[r].z * s, acc[r].w * s));
            uint2 pk;
            pk.x = *(unsigned int*)&p0;
            pk.y = *(unsigned int*)&p1;
            *(uint2*)(C + (size_t)grow * 128 + tx * 4) = pk;
        }
    }
}

// ---------------- GCN aggregation over pre-scaled bf16 h, bf16 out ----------------
__global__ __launch_bounds__(256) void agg_kernel(const __hip_bfloat16* __restrict__ h,
                                                  const float* __restrict__ dis,
                                                  const int* __restrict__ row_start,
                                                  const int* __restrict__ csr_src,
                                                  const float* __restrict__ bias,
                                                  __hip_bfloat16* __restrict__ out, int n) {
    int node = blockIdx.x * 4 + (threadIdx.x >> 6);
    if (node >= n) return;
    int lane = threadIdx.x & 63;
    const __hip_bfloat162* hp = (const __hip_bfloat162*)h;
    float dn = dis[node];
    float2 acc = __bfloat1622float2(hp[(size_t)node * 64 + lane]);
    int i0 = row_start[node], i1 = row_start[node + 1];
    int i = i0;
    for (; i + 8 <= i1; i += 8) {
        int s0 = csr_src[i + 0], s1 = csr_src[i + 1];
        int s2 = csr_src[i + 2], s3 = csr_src[i + 3];
        int s4 = csr_src[i + 4], s5 = csr_src[i + 5];
        int s6 = csr_src[i + 6], s7 = csr_src[i + 7];
        float2 v0 = __bfloat1622float2(hp[(size_t)s0 * 64 + lane]);
        float2 v1 = __bfloat1622float2(hp[(size_t)s1 * 64 + lane]);
        float2 v2 = __bfloat1622float2(hp[(size_t)s2 * 64 + lane]);
        float2 v3 = __bfloat1622float2(hp[(size_t)s3 * 64 + lane]);
        float2 v4 = __bfloat1622float2(hp[(size_t)s4 * 64 + lane]);
        float2 v5 = __bfloat1622float2(hp[(size_t)s5 * 64 + lane]);
        float2 v6 = __bfloat1622float2(hp[(size_t)s6 * 64 + lane]);
        float2 v7 = __bfloat1622float2(hp[(size_t)s7 * 64 + lane]);
        acc.x += ((v0.x + v1.x) + (v2.x + v3.x)) + ((v4.x + v5.x) + (v6.x + v7.x));
        acc.y += ((v0.y + v1.y) + (v2.y + v3.y)) + ((v4.y + v5.y) + (v6.y + v7.y));
    }
    for (; i < i1; i++) {
        int s = csr_src[i];
        float2 v = __bfloat1622float2(hp[(size_t)s * 64 + lane]);
        acc.x += v.x;
        acc.y += v.y;
    }
    float2 bb = ((const float2*)bias)[lane];
    acc.x = fmaxf(fmaf(acc.x, dn, bb.x), 0.f);
    acc.y = fmaxf(fmaf(acc.y, dn, bb.y), 0.f);
    __hip_bfloat162 pk = __float22bfloat162_rn(acc);
    ((__hip_bfloat162*)out)[(size_t)node * 64 + lane] = pk;
}

// ---------------- pooling over bf16 h ----------------
#define POOL_CHUNK 256
__global__ __launch_bounds__(128) void pool_kernel(const __hip_bfloat16* __restrict__ h,
                                                   const int* __restrict__ batch,
                                                   float* __restrict__ psum, int n) {
    int tid = threadIdx.x;
    int r0 = blockIdx.x * POOL_CHUNK;
    if (r0 >= n) return;
    int r1 = min(n, r0 + POOL_CHUNK);
    int cur = batch[r0];
    float acc = 0.f;
    for (int r = r0; r < r1; r++) {
        int g = batch[r];
        if (g != cur) {
            atomicAdd(&psum[cur * 128 + tid], acc);
            acc = 0.f;
            cur = g;
        }
        acc += __bfloat162float(h[(size_t)r * 128 + tid]);
    }
    atomicAdd(&psum[cur * 128 + tid], acc);
}

// ---------------- fused final MLP ----------------
__global__ __launch_bounds__(256) void mlp_kernel(const float* __restrict__ psum,
                                                  const int* __restrict__ gstart,
                                                  const float* __restrict__ sv,
                                                  const float* __restrict__ act,
                                                  const float* __restrict__ Wf1,
                                                  const float* __restrict__ bf1,
                                                  const float* __restrict__ Wf2,
                                                  const float* __restrict__ bf2,
                                                  const float* __restrict__ Wo,
                                                  const float* __restrict__ bo,
                                                  float* __restrict__ out) {
    int g = blockIdx.x, tid = threadIdx.x;
    __shared__ float z[224];
    __shared__ float z1[256];
    __shared__ float red[256];
    if (tid < 128) {
        int c = gstart[g + 1] - gstart[g];
        float cnt = fmaxf((float)c, 1.f);
        z[tid] = psum[g * 128 + tid] / cnt;
    } else if (tid < 192) {
        z[tid] = sv[g * 64 + (tid - 128)];
    } else if (tid < 224) {
        z[tid] = act[g * 32 + (tid - 192)];
    }
    __syncthreads();
    float a = bf1[tid];
    for (int k = 0; k < 224; k++) a = fmaf(z[k], Wf1[k * 256 + tid], a);
    z1[tid] = fmaxf(a, 0.f);
    __syncthreads();
    float b = bf2[tid];
    for (int k = 0; k < 256; k++) b = fmaf(z1[k], Wf2[k * 256 + tid], b);
    b = fmaxf(b, 0.f);
    red[tid] = b * Wo[tid];
    __syncthreads();
    for (int off = 128; off > 0; off >>= 1) {
        if (tid < off) red[tid] += red[tid + off];
        __syncthreads();
    }
    if (tid == 0) out[g] = red[0] + bo[0];
}

// ---------------- launch ----------------
extern "C" void kernel_launch(void* const* d_in, const int* in_sizes, int n_in,
                              void* d_out, int out_size, void* d_ws, size_t ws_size,
                              hipStream_t stream) {
    const float* x   = (const float*)d_in[0];
    const int*   eidx = (const int*)d_in[1];
    const int*   batch = (const int*)d_in[2];
    const float* sv  = (const float*)d_in[3];
    const float* act = (const float*)d_in[4];
    const float* W1  = (const float*)d_in[5];
    const float* b1  = (const float*)d_in[6];
    const float* W2  = (const float*)d_in[7];
    const float* b2  = (const float*)d_in[8];
    const float* Wf1 = (const float*)d_in[9];
    const float* bf1 = (const float*)d_in[10];
    const float* Wf2 = (const float*)d_in[11];
    const float* bf2 = (const float*)d_in[12];
    const float* Wo  = (const float*)d_in[13];
    const float* bo  = (const float*)d_in[14];
    float* out = (float*)d_out;

    const int* srcp = eidx;             // edge_index[0]
    const int* dstp = eidx + N_EDGES;   // edge_index[1]

    char* w = (char*)d_ws;
    // contiguous zero region: bhist + gcur + psum
    int* bhist = (int*)w;              w += (size_t)NBUCK * 4;
    int* gcur = (int*)w;               w += (size_t)NBUCK * 4;
    float* psum = (float*)w;           w += (size_t)N_GRAPHS * HDIM * 4;
    int* bucket_base = (int*)w;        w += (size_t)NBUCK * 4;
    int* deg_cnt = (int*)w;            w += (size_t)N_NODES * 4;
    int* row_start = (int*)w;          w += (size_t)(N_NODES + 1) * 4;
    float* dis = (float*)w;            w += (size_t)N_NODES * 4;
    int* gstart = (int*)w;             w += (size_t)(N_GRAPHS + 1) * 4;
    int* bsum = (int*)w;               w += (size_t)SCAN_NB * 4;
    int* csr_src = (int*)w;            w += (size_t)N_EDGES * 4;
    w = (char*)(((uintptr_t)w + 255) & ~(uintptr_t)255);
    __hip_bfloat16* xb = (__hip_bfloat16*)w;    w += (size_t)N_NODES * HDIM * 2;
    __hip_bfloat16* hbuf = (__hip_bfloat16*)w;  w += (size_t)N_NODES * HDIM * 2;
    __hip_bfloat16* abuf = (__hip_bfloat16*)w;  w += (size_t)N_NODES * HDIM * 2;
    // sorted edge list (12.8 MB) aliases hbuf (25.6 MB): consumed before gemm1 writes hbuf
    int2* sorted = (int2*)hbuf;

    int zero_n = 2 * NBUCK + N_GRAPHS * HDIM;
    zero_kernel<<<(zero_n + 255) / 256, 256, 0, stream>>>(bhist, zero_n);
    cvt_bf16_kernel<<<(N_NODES * HDIM / 8 + 255) / 256, 256, 0, stream>>>(x, xb, N_NODES * HDIM / 8);

    // CSR build via bucketed counting sort
    hist_kernel<<<SCAT_NBLK, 256, 0, stream>>>(dstp, bhist, N_EDGES);
    bucket_scan_kernel<<<1, 256, 0, stream>>>(bhist, bucket_base, gcur);
    scatter_kernel<<<SCAT_NBLK, 256, 0, stream>>>(srcp, dstp, gcur, sorted, N_EDGES);
    deg_bucket_kernel<<<NBUCK, 256, 0, stream>>>(sorted, bucket_base, gcur, deg_cnt, dis);
    scan1_kernel<<<SCAN_NB, SCAN_BS, 0, stream>>>(deg_cnt, row_start, bsum, N_NODES);
    scan2_kernel<<<1, 256, 0, stream>>>(bsum, row_start, SCAN_NB, N_NODES);
    scan3_kernel<<<(N_NODES + 255) / 256, 256, 0, stream>>>(row_start, bsum, N_NODES);
    fill_bucket_kernel<<<NBUCK, 256, 0, stream>>>(sorted, bucket_base, gcur, row_start, csr_src);
    graph_bounds_kernel<<<(N_NODES + 255) / 256, 256, 0, stream>>>(batch, gstart, N_NODES, N_GRAPHS);

    int gemm_blocks = (N_NODES + 63) / 64;
    int agg_blocks = (N_NODES + 3) / 4;

    // conv1: h_scaled = (xb @ W1) * dis ; agg+bias+relu -> abuf (bf16)
    gemm_kernel<<<gemm_blocks, 256, 0, stream>>>(xb, W1, dis, hbuf, N_NODES);
    agg_kernel<<<agg_blocks, 256, 0, stream>>>(hbuf, dis, row_start, csr_src, b1, abuf, N_NODES);
    // conv2
    gemm_kernel<<<gemm_blocks, 256, 0, stream>>>(abuf, W2, dis, hbuf, N_NODES);
    agg_kernel<<<agg_blocks, 256, 0, stream>>>(hbuf, dis, row_start, csr_src, b2, abuf, N_NODES);

    // pool + MLP
    pool_kernel<<<(N_NODES + POOL_CHUNK - 1) / POOL_CHUNK, 128, 0, stream>>>(abuf, batch, psum, N_NODES);
    mlp_kernel<<<N_GRAPHS, 256, 0, stream>>>(psum, gstart, sv, act, Wf1, bf1, Wf2, bf2, Wo, bo, out);
}

// Round 6
// 479.592 us; speedup vs baseline: 1.9973x; 1.0851x over previous
//
#include <hip/hip_runtime.h>
#include <hip/hip_bf16.h>
#include <stdint.h>

#define N_NODES 100000
#define N_EDGES 1600000
#define N_GRAPHS 64
#define HDIM 128
#define SCAN_BS 512
#define SCAN_NB ((N_NODES + SCAN_BS - 1) / SCAN_BS)   // 196

#define BUCKET_SHIFT 9
#define NBUCK ((N_NODES + 511) >> 9)                  // 196
#define SCAT_CHUNK 4096
#define SCAT_NBLK ((N_EDGES + SCAT_CHUNK - 1) / SCAT_CHUNK)  // 391

typedef __bf16 bf16x8 __attribute__((ext_vector_type(8)));
typedef float f32x4 __attribute__((ext_vector_type(4)));

// ---------------- utility ----------------
__global__ void zero_kernel(int* __restrict__ p, int n) {
    int i = blockIdx.x * blockDim.x + threadIdx.x;
    if (i < n) p[i] = 0;
}

// Wt[n][k] = bf16(W[k][n]) ; 128x128
__global__ __launch_bounds__(256) void transpose_w_kernel(const float* __restrict__ W,
                                                          __hip_bfloat16* __restrict__ Wt) {
    int n = blockIdx.x * 2 + (threadIdx.x >> 7);
    int k = threadIdx.x & 127;
    Wt[n * 128 + k] = __float2bfloat16(W[k * 128 + n]);
}

// ---------------- bucketed counting sort of edges by dst ----------------
__global__ __launch_bounds__(256) void hist_kernel(const int* __restrict__ dst,
                                                   int* __restrict__ bhist, int E) {
    __shared__ int hist[NBUCK];
    int tid = threadIdx.x;
    if (tid < NBUCK) hist[tid] = 0;
    __syncthreads();
    int e0 = blockIdx.x * SCAT_CHUNK;
#pragma unroll
    for (int j = 0; j < SCAT_CHUNK / 256; j++) {
        int e = e0 + (j << 8) + tid;
        if (e < E) atomicAdd(&hist[dst[e] >> BUCKET_SHIFT], 1);
    }
    __syncthreads();
    if (tid < NBUCK && hist[tid] > 0) atomicAdd(&bhist[tid], hist[tid]);
}

__global__ __launch_bounds__(256) void bucket_scan_kernel(const int* __restrict__ bhist,
                                                          int* __restrict__ bucket_base,
                                                          int* __restrict__ gcur) {
    __shared__ int s[256];
    int tid = threadIdx.x;
    int v = (tid < NBUCK) ? bhist[tid] : 0;
    s[tid] = v;
    __syncthreads();
#pragma unroll
    for (int off = 1; off < 256; off <<= 1) {
        int t = (tid >= off) ? s[tid - off] : 0;
        __syncthreads();
        s[tid] += t;
        __syncthreads();
    }
    if (tid < NBUCK) {
        int excl = s[tid] - v;
        bucket_base[tid] = excl;
        gcur[tid] = excl;
    }
}

__global__ __launch_bounds__(256) void scatter_kernel(const int* __restrict__ src,
                                                      const int* __restrict__ dst,
                                                      int* __restrict__ gcur,
                                                      int2* __restrict__ sorted, int E) {
    __shared__ int hist[NBUCK];
    __shared__ int base_s[NBUCK];
    int tid = threadIdx.x;
    int e0 = blockIdx.x * SCAT_CHUNK;
    int sv[SCAT_CHUNK / 256], dv[SCAT_CHUNK / 256];
#pragma unroll
    for (int j = 0; j < SCAT_CHUNK / 256; j++) {
        int e = e0 + (j << 8) + tid;
        if (e < E) { sv[j] = src[e]; dv[j] = dst[e]; } else { sv[j] = -1; dv[j] = -1; }
    }
    if (tid < NBUCK) hist[tid] = 0;
    __syncthreads();
#pragma unroll
    for (int j = 0; j < SCAT_CHUNK / 256; j++)
        if (dv[j] >= 0) atomicAdd(&hist[dv[j] >> BUCKET_SHIFT], 1);
    __syncthreads();
    if (tid < NBUCK) {
        int c = hist[tid];
        base_s[tid] = (c > 0) ? atomicAdd(&gcur[tid], c) : 0;
    }
    __syncthreads();
    if (tid < NBUCK) hist[tid] = 0;
    __syncthreads();
#pragma unroll
    for (int j = 0; j < SCAT_CHUNK / 256; j++) {
        if (dv[j] >= 0) {
            int b = dv[j] >> BUCKET_SHIFT;
            int idx = atomicAdd(&hist[b], 1);
            sorted[base_s[b] + idx] = make_int2(sv[j], dv[j]);
        }
    }
}

__global__ __launch_bounds__(256) void deg_bucket_kernel(const int2* __restrict__ sorted,
                                                         const int* __restrict__ bucket_base,
                                                         const int* __restrict__ gcur,
                                                         int* __restrict__ deg_cnt,
                                                         float* __restrict__ dis) {
    __shared__ int cnt[512];
    int b = blockIdx.x, tid = threadIdx.x;
    cnt[tid] = 0; cnt[tid + 256] = 0;
    __syncthreads();
    int node0 = b << BUCKET_SHIFT;
    int lo = bucket_base[b], hi = gcur[b];
    for (int i = lo + tid; i < hi; i += 256)
        atomicAdd(&cnt[sorted[i].y - node0], 1);
    __syncthreads();
#pragma unroll
    for (int k = 0; k < 2; k++) {
        int li = tid + k * 256;
        int node = node0 + li;
        if (node < N_NODES) {
            int c = cnt[li];
            deg_cnt[node] = c;
            dis[node] = rsqrtf((float)c + 1.0f);
        }
    }
}

__global__ __launch_bounds__(256) void fill_bucket_kernel(const int2* __restrict__ sorted,
                                                          const int* __restrict__ bucket_base,
                                                          const int* __restrict__ gcur,
                                                          const int* __restrict__ row_start,
                                                          int* __restrict__ csr_src) {
    __shared__ int posl[512];
    int b = blockIdx.x, tid = threadIdx.x;
    posl[tid] = 0; posl[tid + 256] = 0;
    __syncthreads();
    int node0 = b << BUCKET_SHIFT;
    int lo = bucket_base[b], hi = gcur[b];
    for (int i = lo + tid; i < hi; i += 256) {
        int2 e = sorted[i];
        int idx = atomicAdd(&posl[e.y - node0], 1);
        csr_src[row_start[e.y] + idx] = e.x;
    }
}

// ---------- 3-phase device-wide exclusive scan ----------
__global__ __launch_bounds__(SCAN_BS) void scan1_kernel(const int* __restrict__ cnt,
                                                        int* __restrict__ row_start,
                                                        int* __restrict__ bsum, int n) {
    __shared__ int s[SCAN_BS];
    int tid = threadIdx.x;
    int i = blockIdx.x * SCAN_BS + tid;
    int v = (i < n) ? cnt[i] : 0;
    s[tid] = v;
    __syncthreads();
#pragma unroll
    for (int off = 1; off < SCAN_BS; off <<= 1) {
        int t = (tid >= off) ? s[tid - off] : 0;
        __syncthreads();
        s[tid] += t;
        __syncthreads();
    }
    if (i < n) row_start[i] = s[tid] - v;
    if (tid == SCAN_BS - 1) bsum[blockIdx.x] = s[SCAN_BS - 1];
}

__global__ __launch_bounds__(256) void scan2_kernel(int* __restrict__ bsum,
                                                    int* __restrict__ row_start,
                                                    int nb, int n) {
    __shared__ int s[256];
    int tid = threadIdx.x;
    int v = (tid < nb) ? bsum[tid] : 0;
    s[tid] = v;
    __syncthreads();
#pragma unroll
    for (int off = 1; off < 256; off <<= 1) {
        int t = (tid >= off) ? s[tid - off] : 0;
        __syncthreads();
        s[tid] += t;
        __syncthreads();
    }
    if (tid < nb) bsum[tid] = s[tid] - v;
    if (tid == 255) row_start[n] = s[255];
}

__global__ void scan3_kernel(int* __restrict__ row_start, const int* __restrict__ bsum, int n) {
    int i = blockIdx.x * blockDim.x + threadIdx.x;
    if (i < n) row_start[i] += bsum[i / SCAN_BS];
}

__global__ void graph_bounds_kernel(const int* __restrict__ batch, int* __restrict__ gstart,
                                    int n, int G) {
    int i = blockIdx.x * blockDim.x + threadIdx.x;
    if (i >= n) return;
    int b = batch[i];
    int prev = (i == 0) ? -1 : batch[i - 1];
    for (int g = prev + 1; g <= b; ++g) gstart[g] = i;
    if (i == n - 1) {
        for (int g = b + 1; g <= G; ++g) gstart[g] = n;
    }
}

// ---------------- MFMA GEMM: C[r][c] = bf16( (sum_k A[r][k] W[k][c]) * scale[r] )
// A: fp32 or bf16 [nrows x 128]; Wt: bf16 W^T [128 x 128] (Wt[n][k] = W[k][n])
// Block: 256 thr = 4 waves; 64 rows/block; wave w does rows [16w,16w+16), all 128 cols.
template<bool A_FP32>
__global__ __launch_bounds__(256) void gemm_mfma_kernel(const void* __restrict__ Av,
                                                        const __hip_bfloat16* __restrict__ Wt,
                                                        const float* __restrict__ scale,
                                                        __hip_bfloat16* __restrict__ C, int nrows) {
    __shared__ float Cs[64 * 132];   // row stride 132 floats (pad 4: quad spread, float4-aligned)
    int tid = threadIdx.x;
    int wave = tid >> 6, lane = tid & 63;
    int quad = lane >> 4, l16 = lane & 15;
    int row0 = blockIdx.x * 64;
    int arow = row0 + wave * 16 + l16;
    int arow_c = min(arow, nrows - 1);

    const __hip_bfloat16* A16 = (const __hip_bfloat16*)Av;
    const float* A32 = (const float*)Av;

    f32x4 acc[8];
#pragma unroll
    for (int t = 0; t < 8; t++) acc[t] = (f32x4){0.f, 0.f, 0.f, 0.f};

#pragma unroll
    for (int kt = 0; kt < 4; kt++) {
        int kbase = kt * 32 + quad * 8;
        union { bf16x8 v; __hip_bfloat16 h[8]; uint4 u; } au;
        if (A_FP32) {
            const float* ap = A32 + (size_t)arow_c * 128 + kbase;
            float4 u0 = *(const float4*)ap;
            float4 u1 = *(const float4*)(ap + 4);
            au.h[0] = __float2bfloat16(u0.x); au.h[1] = __float2bfloat16(u0.y);
            au.h[2] = __float2bfloat16(u0.z); au.h[3] = __float2bfloat16(u0.w);
            au.h[4] = __float2bfloat16(u1.x); au.h[5] = __float2bfloat16(u1.y);
            au.h[6] = __float2bfloat16(u1.z); au.h[7] = __float2bfloat16(u1.w);
        } else {
            au.u = *(const uint4*)(A16 + (size_t)arow_c * 128 + kbase);
        }
#pragma unroll
        for (int t = 0; t < 8; t++) {
            bf16x8 b = *(const bf16x8*)(Wt + (size_t)(t * 16 + l16) * 128 + kbase);
            acc[t] = __builtin_amdgcn_mfma_f32_16x16x32_bf16(au.v, b, acc[t], 0, 0, 0);
        }
    }

    // scale rows, stage into LDS (C/D layout: row = quad*4+r, col = t*16+l16)
    int rbase = wave * 16 + quad * 4;
    float s[4];
#pragma unroll
    for (int r = 0; r < 4; r++) s[r] = scale[min(row0 + rbase + r, nrows - 1)];
#pragma unroll
    for (int t = 0; t < 8; t++) {
#pragma unroll
        for (int r = 0; r < 4; r++)
            Cs[(rbase + r) * 132 + t * 16 + l16] = acc[t][r] * s[r];
    }
    __syncthreads();

    // coalesced bf16 writeback: 1024 groups of 8 floats
#pragma unroll
    for (int p = 0; p < 4; p++) {
        int g = p * 256 + tid;
        int row = g >> 4, c8 = (g & 15) * 8;
        int grow = row0 + row;
        if (grow < nrows) {
            const float* cp = &Cs[row * 132 + c8];
            float4 v0 = *(const float4*)cp;
            float4 v1 = *(const float4*)(cp + 4);
            __hip_bfloat162 p0 = __float22bfloat162_rn(make_float2(v0.x, v0.y));
            __hip_bfloat162 p1 = __float22bfloat162_rn(make_float2(v0.z, v0.w));
            __hip_bfloat162 p2 = __float22bfloat162_rn(make_float2(v1.x, v1.y));
            __hip_bfloat162 p3 = __float22bfloat162_rn(make_float2(v1.z, v1.w));
            uint4 pk;
            pk.x = *(unsigned int*)&p0; pk.y = *(unsigned int*)&p1;
            pk.z = *(unsigned int*)&p2; pk.w = *(unsigned int*)&p3;
            *(uint4*)(C + (size_t)grow * 128 + c8) = pk;
        }
    }
}

// ---------------- GCN aggregation over pre-scaled bf16 h, bf16 out ----------------
__global__ __launch_bounds__(256) void agg_kernel(const __hip_bfloat16* __restrict__ h,
                                                  const float* __restrict__ dis,
                                                  const int* __restrict__ row_start,
                                                  const int* __restrict__ csr_src,
                                                  const float* __restrict__ bias,
                                                  __hip_bfloat16* __restrict__ out, int n) {
    int node = blockIdx.x * 4 + (threadIdx.x >> 6);
    if (node >= n) return;
    int lane = threadIdx.x & 63;
    const __hip_bfloat162* hp = (const __hip_bfloat162*)h;
    float dn = dis[node];
    float2 acc = __bfloat1622float2(hp[(size_t)node * 64 + lane]);
    int i0 = row_start[node], i1 = row_start[node + 1];
    int i = i0;
    for (; i + 8 <= i1; i += 8) {
        int s0 = csr_src[i + 0], s1 = csr_src[i + 1];
        int s2 = csr_src[i + 2], s3 = csr_src[i + 3];
        int s4 = csr_src[i + 4], s5 = csr_src[i + 5];
        int s6 = csr_src[i + 6], s7 = csr_src[i + 7];
        float2 v0 = __bfloat1622float2(hp[(size_t)s0 * 64 + lane]);
        float2 v1 = __bfloat1622float2(hp[(size_t)s1 * 64 + lane]);
        float2 v2 = __bfloat1622float2(hp[(size_t)s2 * 64 + lane]);
        float2 v3 = __bfloat1622float2(hp[(size_t)s3 * 64 + lane]);
        float2 v4 = __bfloat1622float2(hp[(size_t)s4 * 64 + lane]);
        float2 v5 = __bfloat1622float2(hp[(size_t)s5 * 64 + lane]);
        float2 v6 = __bfloat1622float2(hp[(size_t)s6 * 64 + lane]);
        float2 v7 = __bfloat1622float2(hp[(size_t)s7 * 64 + lane]);
        acc.x += ((v0.x + v1.x) + (v2.x + v3.x)) + ((v4.x + v5.x) + (v6.x + v7.x));
        acc.y += ((v0.y + v1.y) + (v2.y + v3.y)) + ((v4.y + v5.y) + (v6.y + v7.y));
    }
    for (; i < i1; i++) {
        int s = csr_src[i];
        float2 v = __bfloat1622float2(hp[(size_t)s * 64 + lane]);
        acc.x += v.x;
        acc.y += v.y;
    }
    float2 bb = ((const float2*)bias)[lane];
    acc.x = fmaxf(fmaf(acc.x, dn, bb.x), 0.f);
    acc.y = fmaxf(fmaf(acc.y, dn, bb.y), 0.f);
    __hip_bfloat162 pk = __float22bfloat162_rn(acc);
    ((__hip_bfloat162*)out)[(size_t)node * 64 + lane] = pk;
}

// ---------------- pooling over bf16 h ----------------
#define POOL_CHUNK 256
__global__ __launch_bounds__(128) void pool_kernel(const __hip_bfloat16* __restrict__ h,
                                                   const int* __restrict__ batch,
                                                   float* __restrict__ psum, int n) {
    int tid = threadIdx.x;
    int r0 = blockIdx.x * POOL_CHUNK;
    if (r0 >= n) return;
    int r1 = min(n, r0 + POOL_CHUNK);
    int cur = batch[r0];
    float acc = 0.f;
    for (int r = r0; r < r1; r++) {
        int g = batch[r];
        if (g != cur) {
            atomicAdd(&psum[cur * 128 + tid], acc);
            acc = 0.f;
            cur = g;
        }
        acc += __bfloat162float(h[(size_t)r * 128 + tid]);
    }
    atomicAdd(&psum[cur * 128 + tid], acc);
}

// ---------------- fused final MLP ----------------
__global__ __launch_bounds__(256) void mlp_kernel(const float* __restrict__ psum,
                                                  const int* __restrict__ gstart,
                                                  const float* __restrict__ sv,
                                                  const float* __restrict__ act,
                                                  const float* __restrict__ Wf1,
                                                  const float* __restrict__ bf1,
                                                  const float* __restrict__ Wf2,
                                                  const float* __restrict__ bf2,
                                                  const float* __restrict__ Wo,
                                                  const float* __restrict__ bo,
                                                  float* __restrict__ out) {
    int g = blockIdx.x, tid = threadIdx.x;
    __shared__ float z[224];
    __shared__ float z1[256];
    __shared__ float red[256];
    if (tid < 128) {
        int c = gstart[g + 1] - gstart[g];
        float cnt = fmaxf((float)c, 1.f);
        z[tid] = psum[g * 128 + tid] / cnt;
    } else if (tid < 192) {
        z[tid] = sv[g * 64 + (tid - 128)];
    } else if (tid < 224) {
        z[tid] = act[g * 32 + (tid - 192)];
    }
    __syncthreads();
    float a = bf1[tid];
    for (int k = 0; k < 224; k++) a = fmaf(z[k], Wf1[k * 256 + tid], a);
    z1[tid] = fmaxf(a, 0.f);
    __syncthreads();
    float b = bf2[tid];
    for (int k = 0; k < 256; k++) b = fmaf(z1[k], Wf2[k * 256 + tid], b);
    b = fmaxf(b, 0.f);
    red[tid] = b * Wo[tid];
    __syncthreads();
    for (int off = 128; off > 0; off >>= 1) {
        if (tid < off) red[tid] += red[tid + off];
        __syncthreads();
    }
    if (tid == 0) out[g] = red[0] + bo[0];
}

// ---------------- launch ----------------
extern "C" void kernel_launch(void* const* d_in, const int* in_sizes, int n_in,
                              void* d_out, int out_size, void* d_ws, size_t ws_size,
                              hipStream_t stream) {
    const float* x   = (const float*)d_in[0];
    const int*   eidx = (const int*)d_in[1];
    const int*   batch = (const int*)d_in[2];
    const float* sv  = (const float*)d_in[3];
    const float* act = (const float*)d_in[4];
    const float* W1  = (const float*)d_in[5];
    const float* b1  = (const float*)d_in[6];
    const float* W2  = (const float*)d_in[7];
    const float* b2  = (const float*)d_in[8];
    const float* Wf1 = (const float*)d_in[9];
    const float* bf1 = (const float*)d_in[10];
    const float* Wf2 = (const float*)d_in[11];
    const float* bf2 = (const float*)d_in[12];
    const float* Wo  = (const float*)d_in[13];
    const float* bo  = (const float*)d_in[14];
    float* out = (float*)d_out;

    const int* srcp = eidx;             // edge_index[0]
    const int* dstp = eidx + N_EDGES;   // edge_index[1]

    char* w = (char*)d_ws;
    // contiguous zero region: bhist + gcur + psum
    int* bhist = (int*)w;              w += (size_t)NBUCK * 4;
    int* gcur = (int*)w;               w += (size_t)NBUCK * 4;
    float* psum = (float*)w;           w += (size_t)N_GRAPHS * HDIM * 4;
    int* bucket_base = (int*)w;        w += (size_t)NBUCK * 4;
    int* deg_cnt = (int*)w;            w += (size_t)N_NODES * 4;
    int* row_start = (int*)w;          w += (size_t)(N_NODES + 1) * 4;
    float* dis = (float*)w;            w += (size_t)N_NODES * 4;
    int* gstart = (int*)w;             w += (size_t)(N_GRAPHS + 1) * 4;
    int* bsum = (int*)w;               w += (size_t)SCAN_NB * 4;
    int* csr_src = (int*)w;            w += (size_t)N_EDGES * 4;
    w = (char*)(((uintptr_t)w + 255) & ~(uintptr_t)255);
    __hip_bfloat16* Wt1 = (__hip_bfloat16*)w;   w += (size_t)HDIM * HDIM * 2;
    __hip_bfloat16* Wt2 = (__hip_bfloat16*)w;   w += (size_t)HDIM * HDIM * 2;
    w = (char*)(((uintptr_t)w + 255) & ~(uintptr_t)255);
    __hip_bfloat16* hbuf = (__hip_bfloat16*)w;  w += (size_t)N_NODES * HDIM * 2;
    __hip_bfloat16* abuf = (__hip_bfloat16*)w;  w += (size_t)N_NODES * HDIM * 2;
    // sorted edge list (12.8 MB) aliases hbuf (25.6 MB): consumed before gemm1 writes hbuf
    int2* sorted = (int2*)hbuf;

    int zero_n = 2 * NBUCK + N_GRAPHS * HDIM;
    zero_kernel<<<(zero_n + 255) / 256, 256, 0, stream>>>(bhist, zero_n);
    transpose_w_kernel<<<64, 256, 0, stream>>>(W1, Wt1);
    transpose_w_kernel<<<64, 256, 0, stream>>>(W2, Wt2);

    // CSR build via bucketed counting sort
    hist_kernel<<<SCAT_NBLK, 256, 0, stream>>>(dstp, bhist, N_EDGES);
    bucket_scan_kernel<<<1, 256, 0, stream>>>(bhist, bucket_base, gcur);
    scatter_kernel<<<SCAT_NBLK, 256, 0, stream>>>(srcp, dstp, gcur, sorted, N_EDGES);
    deg_bucket_kernel<<<NBUCK, 256, 0, stream>>>(sorted, bucket_base, gcur, deg_cnt, dis);
    scan1_kernel<<<SCAN_NB, SCAN_BS, 0, stream>>>(deg_cnt, row_start, bsum, N_NODES);
    scan2_kernel<<<1, 256, 0, stream>>>(bsum, row_start, SCAN_NB, N_NODES);
    scan3_kernel<<<(N_NODES + 255) / 256, 256, 0, stream>>>(row_start, bsum, N_NODES);
    fill_bucket_kernel<<<NBUCK, 256, 0, stream>>>(sorted, bucket_base, gcur, row_start, csr_src);
    graph_bounds_kernel<<<(N_NODES + 255) / 256, 256, 0, stream>>>(batch, gstart, N_NODES, N_GRAPHS);

    int gemm_blocks = (N_NODES + 63) / 64;
    int agg_blocks = (N_NODES + 3) / 4;

    // conv1: h_scaled = (x @ W1) * dis ; agg+bias+relu -> abuf (bf16)
    gemm_mfma_kernel<true><<<gemm_blocks, 256, 0, stream>>>(x, Wt1, dis, hbuf, N_NODES);
    agg_kernel<<<agg_blocks, 256, 0, stream>>>(hbuf, dis, row_start, csr_src, b1, abuf, N_NODES);
    // conv2
    gemm_mfma_kernel<false><<<gemm_blocks, 256, 0, stream>>>(abuf, Wt2, dis, hbuf, N_NODES);
    agg_kernel<<<agg_blocks, 256, 0, stream>>>(hbuf, dis, row_start, csr_src, b2, abuf, N_NODES);

    // pool + MLP
    pool_kernel<<<(N_NODES + POOL_CHUNK - 1) / POOL_CHUNK, 128, 0, stream>>>(abuf, batch, psum, N_NODES);
    mlp_kernel<<<N_GRAPHS, 256, 0, stream>>>(psum, gstart, sv, act, Wf1, bf1, Wf2, bf2, Wo, bo, out);
}

// Round 7
// 440.629 us; speedup vs baseline: 2.1739x; 1.0884x over previous
//
#include <hip/hip_runtime.h>
#include <hip/hip_bf16.h>
#include <stdint.h>

#define N_NODES 100000
#define N_EDGES 1600000
#define N_GRAPHS 64
#define HDIM 128

#define BUCKET_SHIFT 9
#define NBUCK ((N_NODES + 511) >> 9)                  // 196
#define CAP 9216                                      // per-bucket edge capacity (mean 8192 + 11 sigma)
#define SCAT_CHUNK 4096
#define SCAT_NBLK ((N_EDGES + SCAT_CHUNK - 1) / SCAT_CHUNK)  // 391

typedef __bf16 bf16x8 __attribute__((ext_vector_type(8)));
typedef float f32x4 __attribute__((ext_vector_type(4)));
typedef float f32x2 __attribute__((ext_vector_type(2)));

// ---------------- init: gcur[b] = b*CAP ; psum = 0 ----------------
__global__ void init_kernel(int* __restrict__ gcur, float* __restrict__ psum) {
    int i = blockIdx.x * blockDim.x + threadIdx.x;
    if (i < NBUCK) gcur[i] = i * CAP;
    int j = i - NBUCK;
    if (j >= 0 && j < N_GRAPHS * HDIM) psum[j] = 0.f;
}

// Wt[n][k] = bf16(W[k][n]) for both weight matrices
__global__ __launch_bounds__(256) void transpose_w2_kernel(const float* __restrict__ W1,
                                                           const float* __restrict__ W2,
                                                           __hip_bfloat16* __restrict__ Wt1,
                                                           __hip_bfloat16* __restrict__ Wt2) {
    int bid = blockIdx.x;                       // 128 blocks
    const float* W = (bid < 64) ? W1 : W2;
    __hip_bfloat16* Wt = (bid < 64) ? Wt1 : Wt2;
    int bb = bid & 63;
    int n = bb * 2 + (threadIdx.x >> 7);
    int k = threadIdx.x & 127;
    Wt[n * 128 + k] = __float2bfloat16(W[k * 128 + n]);
}

// ---------------- scatter edges into capacity-strided buckets ----------------
__global__ __launch_bounds__(256) void scatter_kernel(const int* __restrict__ src,
                                                      const int* __restrict__ dst,
                                                      int* __restrict__ gcur,
                                                      int2* __restrict__ sorted, int E) {
    __shared__ int hist[NBUCK];
    __shared__ int base_s[NBUCK];
    int tid = threadIdx.x;
    int e0 = blockIdx.x * SCAT_CHUNK;
    int sv[SCAT_CHUNK / 256], dv[SCAT_CHUNK / 256];
#pragma unroll
    for (int j = 0; j < SCAT_CHUNK / 256; j++) {
        int e = e0 + (j << 8) + tid;
        if (e < E) { sv[j] = src[e]; dv[j] = dst[e]; } else { sv[j] = -1; dv[j] = -1; }
    }
    if (tid < NBUCK) hist[tid] = 0;
    __syncthreads();
#pragma unroll
    for (int j = 0; j < SCAT_CHUNK / 256; j++)
        if (dv[j] >= 0) atomicAdd(&hist[dv[j] >> BUCKET_SHIFT], 1);
    __syncthreads();
    if (tid < NBUCK) {
        int c = hist[tid];
        base_s[tid] = (c > 0) ? atomicAdd(&gcur[tid], c) : 0;
    }
    __syncthreads();
    if (tid < NBUCK) hist[tid] = 0;
    __syncthreads();
#pragma unroll
    for (int j = 0; j < SCAT_CHUNK / 256; j++) {
        if (dv[j] >= 0) {
            int b = dv[j] >> BUCKET_SHIFT;
            int idx = atomicAdd(&hist[b], 1);
            sorted[base_s[b] + idx] = make_int2(sv[j], dv[j]);
        }
    }
}

// ---------------- per-bucket: degree, dis, row (start,end), CSR fill — one kernel ----------------
__global__ __launch_bounds__(256) void bucket_build_kernel(const int2* __restrict__ sorted,
                                                           const int* __restrict__ gcur,
                                                           int2* __restrict__ rs2,
                                                           float* __restrict__ dis,
                                                           int* __restrict__ csr_src) {
    __shared__ int cnt[512];
    __shared__ int excl[512];
    __shared__ int ps[256];
    int b = blockIdx.x, tid = threadIdx.x;
    cnt[tid] = 0; cnt[tid + 256] = 0;
    __syncthreads();
    int node0 = b << BUCKET_SHIFT;
    int lo = b * CAP, hi = gcur[b];
    for (int i = lo + tid; i < hi; i += 256)
        atomicAdd(&cnt[sorted[i].y - node0], 1);
    __syncthreads();
    // pair-scan of 512 counts with 256 threads
    int c0 = cnt[2 * tid], c1 = cnt[2 * tid + 1];
    ps[tid] = c0 + c1;
    __syncthreads();
#pragma unroll
    for (int off = 1; off < 256; off <<= 1) {
        int t = (tid >= off) ? ps[tid - off] : 0;
        __syncthreads();
        ps[tid] += t;
        __syncthreads();
    }
    int pex = ps[tid] - (c0 + c1);
    excl[2 * tid] = pex;
    excl[2 * tid + 1] = pex + c0;
    __syncthreads();
#pragma unroll
    for (int k = 0; k < 2; k++) {
        int li = tid + k * 256;
        int node = node0 + li;
        if (node < N_NODES) {
            int st = lo + excl[li];
            int c = cnt[li];
            rs2[node] = make_int2(st, st + c);
            dis[node] = rsqrtf((float)c + 1.0f);
        }
    }
    // reuse cnt as fill cursors
    cnt[tid] = 0; cnt[tid + 256] = 0;
    __syncthreads();
    for (int i = lo + tid; i < hi; i += 256) {
        int2 e = sorted[i];
        int li = e.y - node0;
        int idx = atomicAdd(&cnt[li], 1);
        csr_src[lo + excl[li] + idx] = e.x;
    }
}

__global__ void graph_bounds_kernel(const int* __restrict__ batch, int* __restrict__ gstart,
                                    int n, int G) {
    int i = blockIdx.x * blockDim.x + threadIdx.x;
    if (i >= n) return;
    int b = batch[i];
    int prev = (i == 0) ? -1 : batch[i - 1];
    for (int g = prev + 1; g <= b; ++g) gstart[g] = i;
    if (i == n - 1) {
        for (int g = b + 1; g <= G; ++g) gstart[g] = n;
    }
}

// ---------------- MFMA GEMM: C_fp8[r][c] = e4m3( (sum_k A[r][k] W[k][c]) * scale[r] )
// A: fp32 or bf16 [nrows x 128]; Wt: bf16 W^T; C: fp8 e4m3 rows of 128 B
template<bool A_FP32>
__global__ __launch_bounds__(256) void gemm_mfma_kernel(const void* __restrict__ Av,
                                                        const __hip_bfloat16* __restrict__ Wt,
                                                        const float* __restrict__ scale,
                                                        unsigned char* __restrict__ C, int nrows) {
    __shared__ float Cs[64 * 132];
    int tid = threadIdx.x;
    int wave = tid >> 6, lane = tid & 63;
    int quad = lane >> 4, l16 = lane & 15;
    int row0 = blockIdx.x * 64;
    int arow = row0 + wave * 16 + l16;
    int arow_c = min(arow, nrows - 1);

    const __hip_bfloat16* A16 = (const __hip_bfloat16*)Av;
    const float* A32 = (const float*)Av;

    f32x4 acc[8];
#pragma unroll
    for (int t = 0; t < 8; t++) acc[t] = (f32x4){0.f, 0.f, 0.f, 0.f};

#pragma unroll
    for (int kt = 0; kt < 4; kt++) {
        int kbase = kt * 32 + quad * 8;
        union { bf16x8 v; __hip_bfloat16 h[8]; uint4 u; } au;
        if (A_FP32) {
            const float* ap = A32 + (size_t)arow_c * 128 + kbase;
            float4 u0 = *(const float4*)ap;
            float4 u1 = *(const float4*)(ap + 4);
            au.h[0] = __float2bfloat16(u0.x); au.h[1] = __float2bfloat16(u0.y);
            au.h[2] = __float2bfloat16(u0.z); au.h[3] = __float2bfloat16(u0.w);
            au.h[4] = __float2bfloat16(u1.x); au.h[5] = __float2bfloat16(u1.y);
            au.h[6] = __float2bfloat16(u1.z); au.h[7] = __float2bfloat16(u1.w);
        } else {
            au.u = *(const uint4*)(A16 + (size_t)arow_c * 128 + kbase);
        }
#pragma unroll
        for (int t = 0; t < 8; t++) {
            bf16x8 b = *(const bf16x8*)(Wt + (size_t)(t * 16 + l16) * 128 + kbase);
            acc[t] = __builtin_amdgcn_mfma_f32_16x16x32_bf16(au.v, b, acc[t], 0, 0, 0);
        }
    }

    int rbase = wave * 16 + quad * 4;
    float s[4];
#pragma unroll
    for (int r = 0; r < 4; r++) s[r] = scale[min(row0 + rbase + r, nrows - 1)];
#pragma unroll
    for (int t = 0; t < 8; t++) {
#pragma unroll
        for (int r = 0; r < 4; r++)
            Cs[(rbase + r) * 132 + t * 16 + l16] = acc[t][r] * s[r];
    }
    __syncthreads();

    // fp8 writeback: 1024 groups of 8 floats -> 8 bytes each
#pragma unroll
    for (int p = 0; p < 4; p++) {
        int g = p * 256 + tid;
        int row = g >> 4, c8 = (g & 15) * 8;
        int grow = row0 + row;
        if (grow < nrows) {
            const float* cp = &Cs[row * 132 + c8];
            float4 v0 = *(const float4*)cp;
            float4 v1 = *(const float4*)(cp + 4);
            int w0 = __builtin_amdgcn_cvt_pk_fp8_f32(v0.x, v0.y, 0, false);
            w0 = __builtin_amdgcn_cvt_pk_fp8_f32(v0.z, v0.w, w0, true);
            int w1 = __builtin_amdgcn_cvt_pk_fp8_f32(v1.x, v1.y, 0, false);
            w1 = __builtin_amdgcn_cvt_pk_fp8_f32(v1.z, v1.w, w1, true);
            *(uint2*)(C + (size_t)grow * 128 + c8) = make_uint2((unsigned)w0, (unsigned)w1);
        }
    }
}

// ---------------- GCN aggregation over pre-scaled fp8 h, bf16 out ----------------
__device__ __forceinline__ float2 fp8x2_to_f32(unsigned short u) {
    f32x2 f = __builtin_amdgcn_cvt_pk_f32_fp8((int)u, false);
    return make_float2(f[0], f[1]);
}

__global__ __launch_bounds__(256) void agg_kernel(const unsigned char* __restrict__ h8,
                                                  const float* __restrict__ dis,
                                                  const int2* __restrict__ rs2,
                                                  const int* __restrict__ csr_src,
                                                  const float* __restrict__ bias,
                                                  __hip_bfloat16* __restrict__ out, int n) {
    int node = blockIdx.x * 4 + (threadIdx.x >> 6);
    if (node >= n) return;
    int lane = threadIdx.x & 63;
    int boff = lane << 1;                              // byte offset of this lane's 2 features
    float dn = dis[node];
    float2 acc = fp8x2_to_f32(*(const unsigned short*)(h8 + (size_t)node * 128 + boff));
    int2 se = rs2[node];
    int i = se.x, i1 = se.y;
    for (; i + 8 <= i1; i += 8) {
        int s0 = csr_src[i + 0], s1 = csr_src[i + 1];
        int s2 = csr_src[i + 2], s3 = csr_src[i + 3];
        int s4 = csr_src[i + 4], s5 = csr_src[i + 5];
        int s6 = csr_src[i + 6], s7 = csr_src[i + 7];
        unsigned short u0 = *(const unsigned short*)(h8 + (size_t)s0 * 128 + boff);
        unsigned short u1 = *(const unsigned short*)(h8 + (size_t)s1 * 128 + boff);
        unsigned short u2 = *(const unsigned short*)(h8 + (size_t)s2 * 128 + boff);
        unsigned short u3 = *(const unsigned short*)(h8 + (size_t)s3 * 128 + boff);
        unsigned short u4 = *(const unsigned short*)(h8 + (size_t)s4 * 128 + boff);
        unsigned short u5 = *(const unsigned short*)(h8 + (size_t)s5 * 128 + boff);
        unsigned short u6 = *(const unsigned short*)(h8 + (size_t)s6 * 128 + boff);
        unsigned short u7 = *(const unsigned short*)(h8 + (size_t)s7 * 128 + boff);
        float2 v0 = fp8x2_to_f32(u0), v1 = fp8x2_to_f32(u1);
        float2 v2 = fp8x2_to_f32(u2), v3 = fp8x2_to_f32(u3);
        float2 v4 = fp8x2_to_f32(u4), v5 = fp8x2_to_f32(u5);
        float2 v6 = fp8x2_to_f32(u6), v7 = fp8x2_to_f32(u7);
        acc.x += ((v0.x + v1.x) + (v2.x + v3.x)) + ((v4.x + v5.x) + (v6.x + v7.x));
        acc.y += ((v0.y + v1.y) + (v2.y + v3.y)) + ((v4.y + v5.y) + (v6.y + v7.y));
    }
    for (; i < i1; i++) {
        int s = csr_src[i];
        float2 v = fp8x2_to_f32(*(const unsigned short*)(h8 + (size_t)s * 128 + boff));
        acc.x += v.x;
        acc.y += v.y;
    }
    float2 bb = ((const float2*)bias)[lane];
    acc.x = fmaxf(fmaf(acc.x, dn, bb.x), 0.f);
    acc.y = fmaxf(fmaf(acc.y, dn, bb.y), 0.f);
    __hip_bfloat162 pk = __float22bfloat162_rn(acc);
    ((__hip_bfloat162*)out)[(size_t)node * 64 + lane] = pk;
}

// ---------------- pooling over bf16 h ----------------
#define POOL_CHUNK 256
__global__ __launch_bounds__(128) void pool_kernel(const __hip_bfloat16* __restrict__ h,
                                                   const int* __restrict__ batch,
                                                   float* __restrict__ psum, int n) {
    int tid = threadIdx.x;
    int r0 = blockIdx.x * POOL_CHUNK;
    if (r0 >= n) return;
    int r1 = min(n, r0 + POOL_CHUNK);
    int cur = batch[r0];
    float acc = 0.f;
    for (int r = r0; r < r1; r++) {
        int g = batch[r];
        if (g != cur) {
            atomicAdd(&psum[cur * 128 + tid], acc);
            acc = 0.f;
            cur = g;
        }
        acc += __bfloat162float(h[(size_t)r * 128 + tid]);
    }
    atomicAdd(&psum[cur * 128 + tid], acc);
}

// ---------------- fused final MLP ----------------
__global__ __launch_bounds__(256) void mlp_kernel(const float* __restrict__ psum,
                                                  const int* __restrict__ gstart,
                                                  const float* __restrict__ sv,
                                                  const float* __restrict__ act,
                                                  const float* __restrict__ Wf1,
                                                  const float* __restrict__ bf1,
                                                  const float* __restrict__ Wf2,
                                                  const float* __restrict__ bf2,
                                                  const float* __restrict__ Wo,
                                                  const float* __restrict__ bo,
                                                  float* __restrict__ out) {
    int g = blockIdx.x, tid = threadIdx.x;
    __shared__ float z[224];
    __shared__ float z1[256];
    __shared__ float red[256];
    if (tid < 128) {
        int c = gstart[g + 1] - gstart[g];
        float cnt = fmaxf((float)c, 1.f);
        z[tid] = psum[g * 128 + tid] / cnt;
    } else if (tid < 192) {
        z[tid] = sv[g * 64 + (tid - 128)];
    } else if (tid < 224) {
        z[tid] = act[g * 32 + (tid - 192)];
    }
    __syncthreads();
    float a = bf1[tid];
    for (int k = 0; k < 224; k++) a = fmaf(z[k], Wf1[k * 256 + tid], a);
    z1[tid] = fmaxf(a, 0.f);
    __syncthreads();
    float b = bf2[tid];
    for (int k = 0; k < 256; k++) b = fmaf(z1[k], Wf2[k * 256 + tid], b);
    b = fmaxf(b, 0.f);
    red[tid] = b * Wo[tid];
    __syncthreads();
    for (int off = 128; off > 0; off >>= 1) {
        if (tid < off) red[tid] += red[tid + off];
        __syncthreads();
    }
    if (tid == 0) out[g] = red[0] + bo[0];
}

// ---------------- launch ----------------
extern "C" void kernel_launch(void* const* d_in, const int* in_sizes, int n_in,
                              void* d_out, int out_size, void* d_ws, size_t ws_size,
                              hipStream_t stream) {
    const float* x   = (const float*)d_in[0];
    const int*   eidx = (const int*)d_in[1];
    const int*   batch = (const int*)d_in[2];
    const float* sv  = (const float*)d_in[3];
    const float* act = (const float*)d_in[4];
    const float* W1  = (const float*)d_in[5];
    const float* b1  = (const float*)d_in[6];
    const float* W2  = (const float*)d_in[7];
    const float* b2  = (const float*)d_in[8];
    const float* Wf1 = (const float*)d_in[9];
    const float* bf1 = (const float*)d_in[10];
    const float* Wf2 = (const float*)d_in[11];
    const float* bf2 = (const float*)d_in[12];
    const float* Wo  = (const float*)d_in[13];
    const float* bo  = (const float*)d_in[14];
    float* out = (float*)d_out;

    const int* srcp = eidx;             // edge_index[0]
    const int* dstp = eidx + N_EDGES;   // edge_index[1]

    char* w = (char*)d_ws;
    int* gcur = (int*)w;               w += (size_t)NBUCK * 4;
    float* psum = (float*)w;           w += (size_t)N_GRAPHS * HDIM * 4;
    int2* rs2 = (int2*)w;              w += (size_t)N_NODES * 8;
    float* dis = (float*)w;            w += (size_t)N_NODES * 4;
    int* gstart = (int*)w;             w += (size_t)(N_GRAPHS + 1) * 4;
    w = (char*)(((uintptr_t)w + 255) & ~(uintptr_t)255);
    int* csr_src = (int*)w;            w += (size_t)NBUCK * CAP * 4;
    w = (char*)(((uintptr_t)w + 255) & ~(uintptr_t)255);
    int2* sorted = (int2*)w;           w += (size_t)NBUCK * CAP * 8;
    w = (char*)(((uintptr_t)w + 255) & ~(uintptr_t)255);
    __hip_bfloat16* Wt1 = (__hip_bfloat16*)w;   w += (size_t)HDIM * HDIM * 2;
    __hip_bfloat16* Wt2 = (__hip_bfloat16*)w;   w += (size_t)HDIM * HDIM * 2;
    w = (char*)(((uintptr_t)w + 255) & ~(uintptr_t)255);
    unsigned char* hbuf = (unsigned char*)w;    w += (size_t)N_NODES * HDIM;      // fp8
    w = (char*)(((uintptr_t)w + 255) & ~(uintptr_t)255);
    __hip_bfloat16* abuf = (__hip_bfloat16*)w;  w += (size_t)N_NODES * HDIM * 2;  // bf16

    init_kernel<<<(NBUCK + N_GRAPHS * HDIM + 255) / 256, 256, 0, stream>>>(gcur, psum);
    transpose_w2_kernel<<<128, 256, 0, stream>>>(W1, W2, Wt1, Wt2);

    // CSR build: scatter into capacity-strided buckets, then one per-bucket build kernel
    scatter_kernel<<<SCAT_NBLK, 256, 0, stream>>>(srcp, dstp, gcur, sorted, N_EDGES);
    bucket_build_kernel<<<NBUCK, 256, 0, stream>>>(sorted, gcur, rs2, dis, csr_src);
    graph_bounds_kernel<<<(N_NODES + 255) / 256, 256, 0, stream>>>(batch, gstart, N_NODES, N_GRAPHS);

    int gemm_blocks = (N_NODES + 63) / 64;
    int agg_blocks = (N_NODES + 3) / 4;

    // conv1: h_fp8 = e4m3((x @ W1) * dis) ; agg+bias+relu -> abuf (bf16)
    gemm_mfma_kernel<true><<<gemm_blocks, 256, 0, stream>>>(x, Wt1, dis, hbuf, N_NODES);
    agg_kernel<<<agg_blocks, 256, 0, stream>>>(hbuf, dis, rs2, csr_src, b1, abuf, N_NODES);
    // conv2
    gemm_mfma_kernel<false><<<gemm_blocks, 256, 0, stream>>>(abuf, Wt2, dis, hbuf, N_NODES);
    agg_kernel<<<agg_blocks, 256, 0, stream>>>(hbuf, dis, rs2, csr_src, b2, abuf, N_NODES);

    // pool + MLP
    pool_kernel<<<(N_NODES + POOL_CHUNK - 1) / POOL_CHUNK, 128, 0, stream>>>(abuf, batch, psum, N_NODES);
    mlp_kernel<<<N_GRAPHS, 256, 0, stream>>>(psum, gstart, sv, act, Wf1, bf1, Wf2, bf2, Wo, bo, out);
}

// Round 8
// 368.422 us; speedup vs baseline: 2.6000x; 1.1960x over previous
//
#include <hip/hip_runtime.h>
#include <hip/hip_bf16.h>
#include <stdint.h>

#define N_NODES 100000
#define N_EDGES 1600000
#define N_GRAPHS 64
#define HDIM 128

#define BUCKET_SHIFT 9
#define NBUCK ((N_NODES + 511) >> 9)                  // 196
#define CAP 9216                                      // per-bucket edge capacity (mean 8192 + 11 sigma)
#define SCAT_CHUNK 4096
#define SCAT_NBLK ((N_EDGES + SCAT_CHUNK - 1) / SCAT_CHUNK)  // 391

typedef __bf16 bf16x8 __attribute__((ext_vector_type(8)));
typedef float f32x4 __attribute__((ext_vector_type(4)));
typedef float f32x2 __attribute__((ext_vector_type(2)));

// ---------------- init: gcur[b] = b*CAP ; psum = 0 ----------------
__global__ void init_kernel(int* __restrict__ gcur, float* __restrict__ psum) {
    int i = blockIdx.x * blockDim.x + threadIdx.x;
    if (i < NBUCK) gcur[i] = i * CAP;
    int j = i - NBUCK;
    if (j >= 0 && j < N_GRAPHS * HDIM) psum[j] = 0.f;
}

// Wt[n][k] = bf16(W[k][n]) for both weight matrices
__global__ __launch_bounds__(256) void transpose_w2_kernel(const float* __restrict__ W1,
                                                           const float* __restrict__ W2,
                                                           __hip_bfloat16* __restrict__ Wt1,
                                                           __hip_bfloat16* __restrict__ Wt2) {
    int bid = blockIdx.x;                       // 128 blocks
    const float* W = (bid < 64) ? W1 : W2;
    __hip_bfloat16* Wt = (bid < 64) ? Wt1 : Wt2;
    int bb = bid & 63;
    int n = bb * 2 + (threadIdx.x >> 7);
    int k = threadIdx.x & 127;
    Wt[n * 128 + k] = __float2bfloat16(W[k * 128 + n]);
}

// ---------------- scatter edges into capacity-strided buckets ----------------
// packed entry: (local_dst << 17) | src   (src < 2^17, local_dst < 512)
__global__ __launch_bounds__(256) void scatter_kernel(const int* __restrict__ src,
                                                      const int* __restrict__ dst,
                                                      int* __restrict__ gcur,
                                                      int* __restrict__ sorted, int E) {
    __shared__ int hist[NBUCK];
    __shared__ int base_s[NBUCK];
    int tid = threadIdx.x;
    int e0 = blockIdx.x * SCAT_CHUNK;
    int sv[SCAT_CHUNK / 256], dv[SCAT_CHUNK / 256];
#pragma unroll
    for (int j = 0; j < SCAT_CHUNK / 256; j++) {
        int e = e0 + (j << 8) + tid;
        if (e < E) { sv[j] = src[e]; dv[j] = dst[e]; } else { sv[j] = -1; dv[j] = -1; }
    }
    if (tid < NBUCK) hist[tid] = 0;
    __syncthreads();
#pragma unroll
    for (int j = 0; j < SCAT_CHUNK / 256; j++)
        if (dv[j] >= 0) atomicAdd(&hist[dv[j] >> BUCKET_SHIFT], 1);
    __syncthreads();
    if (tid < NBUCK) {
        int c = hist[tid];
        base_s[tid] = (c > 0) ? atomicAdd(&gcur[tid], c) : 0;
    }
    __syncthreads();
    if (tid < NBUCK) hist[tid] = 0;
    __syncthreads();
#pragma unroll
    for (int j = 0; j < SCAT_CHUNK / 256; j++) {
        if (dv[j] >= 0) {
            int b = dv[j] >> BUCKET_SHIFT;
            int idx = atomicAdd(&hist[b], 1);
            sorted[base_s[b] + idx] = ((dv[j] & 511) << 17) | sv[j];
        }
    }
}

// ---------------- per-bucket: degree, dis, row (start,end), CSR fill — one kernel ----------------
__global__ __launch_bounds__(256) void bucket_build_kernel(const int* __restrict__ sorted,
                                                           const int* __restrict__ gcur,
                                                           int2* __restrict__ rs2,
                                                           float* __restrict__ dis,
                                                           int* __restrict__ csr_src) {
    __shared__ int cnt[512];
    __shared__ int excl[512];
    __shared__ int ps[256];
    int b = blockIdx.x, tid = threadIdx.x;
    cnt[tid] = 0; cnt[tid + 256] = 0;
    __syncthreads();
    int node0 = b << BUCKET_SHIFT;
    int lo = b * CAP, hi = gcur[b];
    for (int i = lo + tid; i < hi; i += 256)
        atomicAdd(&cnt[((unsigned)sorted[i]) >> 17], 1);
    __syncthreads();
    // pair-scan of 512 counts with 256 threads
    int c0 = cnt[2 * tid], c1 = cnt[2 * tid + 1];
    ps[tid] = c0 + c1;
    __syncthreads();
#pragma unroll
    for (int off = 1; off < 256; off <<= 1) {
        int t = (tid >= off) ? ps[tid - off] : 0;
        __syncthreads();
        ps[tid] += t;
        __syncthreads();
    }
    int pex = ps[tid] - (c0 + c1);
    excl[2 * tid] = pex;
    excl[2 * tid + 1] = pex + c0;
    __syncthreads();
#pragma unroll
    for (int k = 0; k < 2; k++) {
        int li = tid + k * 256;
        int node = node0 + li;
        if (node < N_NODES) {
            int st = lo + excl[li];
            int c = cnt[li];
            rs2[node] = make_int2(st, st + c);
            dis[node] = rsqrtf((float)c + 1.0f);
        }
    }
    // reuse cnt as fill cursors
    cnt[tid] = 0; cnt[tid + 256] = 0;
    __syncthreads();
    for (int i = lo + tid; i < hi; i += 256) {
        int v = sorted[i];
        int li = ((unsigned)v) >> 17;
        int idx = atomicAdd(&cnt[li], 1);
        csr_src[lo + excl[li] + idx] = v & 0x1FFFF;
    }
}

__global__ void graph_bounds_kernel(const int* __restrict__ batch, int* __restrict__ gstart,
                                    int n, int G) {
    int i = blockIdx.x * blockDim.x + threadIdx.x;
    if (i >= n) return;
    int b = batch[i];
    int prev = (i == 0) ? -1 : batch[i - 1];
    for (int g = prev + 1; g <= b; ++g) gstart[g] = i;
    if (i == n - 1) {
        for (int g = b + 1; g <= G; ++g) gstart[g] = n;
    }
}

// ---------------- MFMA GEMM: C_fp8[r][c] = e4m3( (sum_k A[r][k] W[k][c]) * scale[r] )
template<bool A_FP32>
__global__ __launch_bounds__(256) void gemm_mfma_kernel(const void* __restrict__ Av,
                                                        const __hip_bfloat16* __restrict__ Wt,
                                                        const float* __restrict__ scale,
                                                        unsigned char* __restrict__ C, int nrows) {
    __shared__ float Cs[64 * 132];
    int tid = threadIdx.x;
    int wave = tid >> 6, lane = tid & 63;
    int quad = lane >> 4, l16 = lane & 15;
    int row0 = blockIdx.x * 64;
    int arow = row0 + wave * 16 + l16;
    int arow_c = min(arow, nrows - 1);

    const __hip_bfloat16* A16 = (const __hip_bfloat16*)Av;
    const float* A32 = (const float*)Av;

    f32x4 acc[8];
#pragma unroll
    for (int t = 0; t < 8; t++) acc[t] = (f32x4){0.f, 0.f, 0.f, 0.f};

#pragma unroll
    for (int kt = 0; kt < 4; kt++) {
        int kbase = kt * 32 + quad * 8;
        union { bf16x8 v; __hip_bfloat16 h[8]; uint4 u; } au;
        if (A_FP32) {
            const float* ap = A32 + (size_t)arow_c * 128 + kbase;
            float4 u0 = *(const float4*)ap;
            float4 u1 = *(const float4*)(ap + 4);
            au.h[0] = __float2bfloat16(u0.x); au.h[1] = __float2bfloat16(u0.y);
            au.h[2] = __float2bfloat16(u0.z); au.h[3] = __float2bfloat16(u0.w);
            au.h[4] = __float2bfloat16(u1.x); au.h[5] = __float2bfloat16(u1.y);
            au.h[6] = __float2bfloat16(u1.z); au.h[7] = __float2bfloat16(u1.w);
        } else {
            au.u = *(const uint4*)(A16 + (size_t)arow_c * 128 + kbase);
        }
#pragma unroll
        for (int t = 0; t < 8; t++) {
            bf16x8 b = *(const bf16x8*)(Wt + (size_t)(t * 16 + l16) * 128 + kbase);
            acc[t] = __builtin_amdgcn_mfma_f32_16x16x32_bf16(au.v, b, acc[t], 0, 0, 0);
        }
    }

    int rbase = wave * 16 + quad * 4;
    float s[4];
#pragma unroll
    for (int r = 0; r < 4; r++) s[r] = scale[min(row0 + rbase + r, nrows - 1)];
#pragma unroll
    for (int t = 0; t < 8; t++) {
#pragma unroll
        for (int r = 0; r < 4; r++)
            Cs[(rbase + r) * 132 + t * 16 + l16] = acc[t][r] * s[r];
    }
    __syncthreads();

#pragma unroll
    for (int p = 0; p < 4; p++) {
        int g = p * 256 + tid;
        int row = g >> 4, c8 = (g & 15) * 8;
        int grow = row0 + row;
        if (grow < nrows) {
            const float* cp = &Cs[row * 132 + c8];
            float4 v0 = *(const float4*)cp;
            float4 v1 = *(const float4*)(cp + 4);
            int w0 = __builtin_amdgcn_cvt_pk_fp8_f32(v0.x, v0.y, 0, false);
            w0 = __builtin_amdgcn_cvt_pk_fp8_f32(v0.z, v0.w, w0, true);
            int w1 = __builtin_amdgcn_cvt_pk_fp8_f32(v1.x, v1.y, 0, false);
            w1 = __builtin_amdgcn_cvt_pk_fp8_f32(v1.z, v1.w, w1, true);
            *(uint2*)(C + (size_t)grow * 128 + c8) = make_uint2((unsigned)w0, (unsigned)w1);
        }
    }
}

// ---------------- GCN aggregation over pre-scaled fp8 h, bf16 out ----------------
__device__ __forceinline__ float2 fp8x2_to_f32(unsigned short u) {
    f32x2 f = __builtin_amdgcn_cvt_pk_f32_fp8((int)u, false);
    return make_float2(f[0], f[1]);
}

__global__ __launch_bounds__(256) void agg_kernel(const unsigned char* __restrict__ h8,
                                                  const float* __restrict__ dis,
                                                  const int2* __restrict__ rs2,
                                                  const int* __restrict__ csr_src,
                                                  const float* __restrict__ bias,
                                                  __hip_bfloat16* __restrict__ out, int n) {
    int node = blockIdx.x * 4 + (threadIdx.x >> 6);
    if (node >= n) return;
    int lane = threadIdx.x & 63;
    int boff = lane << 1;
    float dn = dis[node];
    float2 acc = fp8x2_to_f32(*(const unsigned short*)(h8 + (size_t)node * 128 + boff));
    int2 se = rs2[node];
    int i = se.x, i1 = se.y;
    for (; i + 8 <= i1; i += 8) {
        int s0 = csr_src[i + 0], s1 = csr_src[i + 1];
        int s2 = csr_src[i + 2], s3 = csr_src[i + 3];
        int s4 = csr_src[i + 4], s5 = csr_src[i + 5];
        int s6 = csr_src[i + 6], s7 = csr_src[i + 7];
        unsigned short u0 = *(const unsigned short*)(h8 + (size_t)s0 * 128 + boff);
        unsigned short u1 = *(const unsigned short*)(h8 + (size_t)s1 * 128 + boff);
        unsigned short u2 = *(const unsigned short*)(h8 + (size_t)s2 * 128 + boff);
        unsigned short u3 = *(const unsigned short*)(h8 + (size_t)s3 * 128 + boff);
        unsigned short u4 = *(const unsigned short*)(h8 + (size_t)s4 * 128 + boff);
        unsigned short u5 = *(const unsigned short*)(h8 + (size_t)s5 * 128 + boff);
        unsigned short u6 = *(const unsigned short*)(h8 + (size_t)s6 * 128 + boff);
        unsigned short u7 = *(const unsigned short*)(h8 + (size_t)s7 * 128 + boff);
        float2 v0 = fp8x2_to_f32(u0), v1 = fp8x2_to_f32(u1);
        float2 v2 = fp8x2_to_f32(u2), v3 = fp8x2_to_f32(u3);
        float2 v4 = fp8x2_to_f32(u4), v5 = fp8x2_to_f32(u5);
        float2 v6 = fp8x2_to_f32(u6), v7 = fp8x2_to_f32(u7);
        acc.x += ((v0.x + v1.x) + (v2.x + v3.x)) + ((v4.x + v5.x) + (v6.x + v7.x));
        acc.y += ((v0.y + v1.y) + (v2.y + v3.y)) + ((v4.y + v5.y) + (v6.y + v7.y));
    }
    for (; i < i1; i++) {
        int s = csr_src[i];
        float2 v = fp8x2_to_f32(*(const unsigned short*)(h8 + (size_t)s * 128 + boff));
        acc.x += v.x;
        acc.y += v.y;
    }
    float2 bb = ((const float2*)bias)[lane];
    acc.x = fmaxf(fmaf(acc.x, dn, bb.x), 0.f);
    acc.y = fmaxf(fmaf(acc.y, dn, bb.y), 0.f);
    __hip_bfloat162 pk = __float22bfloat162_rn(acc);
    ((__hip_bfloat162*)out)[(size_t)node * 64 + lane] = pk;
}

// ---------------- pooling: 128 rows/block, 16B/lane, gstart-based segments ----------------
#define POOL_ROWS 128
__global__ __launch_bounds__(256) void pool_kernel(const __hip_bfloat16* __restrict__ h,
                                                   const int* __restrict__ batch,
                                                   const int* __restrict__ gstart,
                                                   float* __restrict__ psum, int n) {
    __shared__ float red[16 * 128];
    int tid = threadIdx.x;
    int rr = tid >> 4, fg = tid & 15;
    int r0 = blockIdx.x * POOL_ROWS;
    if (r0 >= n) return;
    int r1 = min(n, r0 + POOL_ROWS);
    int g = batch[r0];
    int seg_lo = r0;
    while (seg_lo < r1) {
        while (gstart[g + 1] <= seg_lo) g++;
        int seg_hi = min(r1, gstart[g + 1]);
        float a[8];
#pragma unroll
        for (int j = 0; j < 8; j++) a[j] = 0.f;
        for (int r = seg_lo + rr; r < seg_hi; r += 16) {
            uint4 u = *(const uint4*)(h + (size_t)r * 128 + fg * 8);
            float2 f0 = __bfloat1622float2(*(__hip_bfloat162*)&u.x);
            float2 f1 = __bfloat1622float2(*(__hip_bfloat162*)&u.y);
            float2 f2 = __bfloat1622float2(*(__hip_bfloat162*)&u.z);
            float2 f3 = __bfloat1622float2(*(__hip_bfloat162*)&u.w);
            a[0] += f0.x; a[1] += f0.y; a[2] += f1.x; a[3] += f1.y;
            a[4] += f2.x; a[5] += f2.y; a[6] += f3.x; a[7] += f3.y;
        }
        *(float4*)&red[rr * 128 + fg * 8] = make_float4(a[0], a[1], a[2], a[3]);
        *(float4*)&red[rr * 128 + fg * 8 + 4] = make_float4(a[4], a[5], a[6], a[7]);
        __syncthreads();
        if (tid < 128) {
            float s = 0.f;
#pragma unroll
            for (int k = 0; k < 16; k++) s += red[k * 128 + tid];
            atomicAdd(&psum[g * 128 + tid], s);
        }
        __syncthreads();
        seg_lo = seg_hi;
    }
}

// ---------------- fused final MLP ----------------
__global__ __launch_bounds__(256) void mlp_kernel(const float* __restrict__ psum,
                                                  const int* __restrict__ gstart,
                                                  const float* __restrict__ sv,
                                                  const float* __restrict__ act,
                                                  const float* __restrict__ Wf1,
                                                  const float* __restrict__ bf1,
                                                  const float* __restrict__ Wf2,
                                                  const float* __restrict__ bf2,
                                                  const float* __restrict__ Wo,
                                                  const float* __restrict__ bo,
                                                  float* __restrict__ out) {
    int g = blockIdx.x, tid = threadIdx.x;
    __shared__ float z[224];
    __shared__ float z1[256];
    __shared__ float red[256];
    if (tid < 128) {
        int c = gstart[g + 1] - gstart[g];
        float cnt = fmaxf((float)c, 1.f);
        z[tid] = psum[g * 128 + tid] / cnt;
    } else if (tid < 192) {
        z[tid] = sv[g * 64 + (tid - 128)];
    } else if (tid < 224) {
        z[tid] = act[g * 32 + (tid - 192)];
    }
    __syncthreads();
    float a = bf1[tid];
    for (int k = 0; k < 224; k++) a = fmaf(z[k], Wf1[k * 256 + tid], a);
    z1[tid] = fmaxf(a, 0.f);
    __syncthreads();
    float b = bf2[tid];
    for (int k = 0; k < 256; k++) b = fmaf(z1[k], Wf2[k * 256 + tid], b);
    b = fmaxf(b, 0.f);
    red[tid] = b * Wo[tid];
    __syncthreads();
    for (int off = 128; off > 0; off >>= 1) {
        if (tid < off) red[tid] += red[tid + off];
        __syncthreads();
    }
    if (tid == 0) out[g] = red[0] + bo[0];
}

// ---------------- launch ----------------
extern "C" void kernel_launch(void* const* d_in, const int* in_sizes, int n_in,
                              void* d_out, int out_size, void* d_ws, size_t ws_size,
                              hipStream_t stream) {
    const float* x   = (const float*)d_in[0];
    const int*   eidx = (const int*)d_in[1];
    const int*   batch = (const int*)d_in[2];
    const float* sv  = (const float*)d_in[3];
    const float* act = (const float*)d_in[4];
    const float* W1  = (const float*)d_in[5];
    const float* b1  = (const float*)d_in[6];
    const float* W2  = (const float*)d_in[7];
    const float* b2  = (const float*)d_in[8];
    const float* Wf1 = (const float*)d_in[9];
    const float* bf1 = (const float*)d_in[10];
    const float* Wf2 = (const float*)d_in[11];
    const float* bf2 = (const float*)d_in[12];
    const float* Wo  = (const float*)d_in[13];
    const float* bo  = (const float*)d_in[14];
    float* out = (float*)d_out;

    const int* srcp = eidx;             // edge_index[0]
    const int* dstp = eidx + N_EDGES;   // edge_index[1]

    char* w = (char*)d_ws;
    int* gcur = (int*)w;               w += (size_t)NBUCK * 4;
    float* psum = (float*)w;           w += (size_t)N_GRAPHS * HDIM * 4;
    int2* rs2 = (int2*)w;              w += (size_t)N_NODES * 8;
    float* dis = (float*)w;            w += (size_t)N_NODES * 4;
    int* gstart = (int*)w;             w += (size_t)(N_GRAPHS + 1) * 4;
    w = (char*)(((uintptr_t)w + 255) & ~(uintptr_t)255);
    int* csr_src = (int*)w;            w += (size_t)NBUCK * CAP * 4;
    w = (char*)(((uintptr_t)w + 255) & ~(uintptr_t)255);
    int* sorted = (int*)w;             w += (size_t)NBUCK * CAP * 4;
    w = (char*)(((uintptr_t)w + 255) & ~(uintptr_t)255);
    __hip_bfloat16* Wt1 = (__hip_bfloat16*)w;   w += (size_t)HDIM * HDIM * 2;
    __hip_bfloat16* Wt2 = (__hip_bfloat16*)w;   w += (size_t)HDIM * HDIM * 2;
    w = (char*)(((uintptr_t)w + 255) & ~(uintptr_t)255);
    unsigned char* hbuf = (unsigned char*)w;    w += (size_t)N_NODES * HDIM;      // fp8
    w = (char*)(((uintptr_t)w + 255) & ~(uintptr_t)255);
    __hip_bfloat16* abuf = (__hip_bfloat16*)w;  w += (size_t)N_NODES * HDIM * 2;  // bf16

    init_kernel<<<(NBUCK + N_GRAPHS * HDIM + 255) / 256, 256, 0, stream>>>(gcur, psum);
    transpose_w2_kernel<<<128, 256, 0, stream>>>(W1, W2, Wt1, Wt2);

    scatter_kernel<<<SCAT_NBLK, 256, 0, stream>>>(srcp, dstp, gcur, sorted, N_EDGES);
    bucket_build_kernel<<<NBUCK, 256, 0, stream>>>(sorted, gcur, rs2, dis, csr_src);
    graph_bounds_kernel<<<(N_NODES + 255) / 256, 256, 0, stream>>>(batch, gstart, N_NODES, N_GRAPHS);

    int gemm_blocks = (N_NODES + 63) / 64;
    int agg_blocks = (N_NODES + 3) / 4;

    gemm_mfma_kernel<true><<<gemm_blocks, 256, 0, stream>>>(x, Wt1, dis, hbuf, N_NODES);
    agg_kernel<<<agg_blocks, 256, 0, stream>>>(hbuf, dis, rs2, csr_src, b1, abuf, N_NODES);
    gemm_mfma_kernel<false><<<gemm_blocks, 256, 0, stream>>>(abuf, Wt2, dis, hbuf, N_NODES);
    agg_kernel<<<agg_blocks, 256, 0, stream>>>(hbuf, dis, rs2, csr_src, b2, abuf, N_NODES);

    pool_kernel<<<(N_NODES + POOL_ROWS - 1) / POOL_ROWS, 256, 0, stream>>>(abuf, batch, gstart, psum, N_NODES);
    mlp_kernel<<<N_GRAPHS, 256, 0, stream>>>(psum, gstart, sv, act, Wf1, bf1, Wf2, bf2, Wo, bo, out);
}

// Round 9
// 363.640 us; speedup vs baseline: 2.6342x; 1.0131x over previous
//
#include <hip/hip_runtime.h>
#include <hip/hip_bf16.h>
#include <stdint.h>

#define N_NODES 100000
#define N_EDGES 1600000
#define N_GRAPHS 64
#define HDIM 128

#define BUCKET_SHIFT 9
#define NBUCK ((N_NODES + 511) >> 9)                  // 196
#define CAP 9216                                      // per-bucket edge capacity (mean 8192 + 11 sigma)
#define SCAT_CHUNK 4096
#define SCAT_NBLK ((N_EDGES + SCAT_CHUNK - 1) / SCAT_CHUNK)  // 391

typedef __bf16 bf16x8 __attribute__((ext_vector_type(8)));
typedef float f32x4 __attribute__((ext_vector_type(4)));
typedef float f32x2 __attribute__((ext_vector_type(2)));

// ---------------- init: gcur[b] = b*CAP ; psum = 0 ----------------
__global__ void init_kernel(int* __restrict__ gcur, float* __restrict__ psum) {
    int i = blockIdx.x * blockDim.x + threadIdx.x;
    if (i < NBUCK) gcur[i] = i * CAP;
    int j = i - NBUCK;
    if (j >= 0 && j < N_GRAPHS * HDIM) psum[j] = 0.f;
}

// Wt[n][k] = bf16(W[k][n]) for both weight matrices
__global__ __launch_bounds__(256) void transpose_w2_kernel(const float* __restrict__ W1,
                                                           const float* __restrict__ W2,
                                                           __hip_bfloat16* __restrict__ Wt1,
                                                           __hip_bfloat16* __restrict__ Wt2) {
    int bid = blockIdx.x;                       // 128 blocks
    const float* W = (bid < 64) ? W1 : W2;
    __hip_bfloat16* Wt = (bid < 64) ? Wt1 : Wt2;
    int bb = bid & 63;
    int n = bb * 2 + (threadIdx.x >> 7);
    int k = threadIdx.x & 127;
    Wt[n * 128 + k] = __float2bfloat16(W[k * 128 + n]);
}

// ---------------- scatter edges into capacity-strided buckets ----------------
// packed entry: (local_dst << 17) | src   (src < 2^17, local_dst < 512)
__global__ __launch_bounds__(256) void scatter_kernel(const int* __restrict__ src,
                                                      const int* __restrict__ dst,
                                                      int* __restrict__ gcur,
                                                      int* __restrict__ sorted, int E) {
    __shared__ int hist[NBUCK];
    __shared__ int base_s[NBUCK];
    int tid = threadIdx.x;
    int e0 = blockIdx.x * SCAT_CHUNK;
    int sv[SCAT_CHUNK / 256], dv[SCAT_CHUNK / 256];
#pragma unroll
    for (int j = 0; j < SCAT_CHUNK / 256; j++) {
        int e = e0 + (j << 8) + tid;
        if (e < E) { sv[j] = src[e]; dv[j] = dst[e]; } else { sv[j] = -1; dv[j] = -1; }
    }
    if (tid < NBUCK) hist[tid] = 0;
    __syncthreads();
#pragma unroll
    for (int j = 0; j < SCAT_CHUNK / 256; j++)
        if (dv[j] >= 0) atomicAdd(&hist[dv[j] >> BUCKET_SHIFT], 1);
    __syncthreads();
    if (tid < NBUCK) {
        int c = hist[tid];
        base_s[tid] = (c > 0) ? atomicAdd(&gcur[tid], c) : 0;
    }
    __syncthreads();
    if (tid < NBUCK) hist[tid] = 0;
    __syncthreads();
#pragma unroll
    for (int j = 0; j < SCAT_CHUNK / 256; j++) {
        if (dv[j] >= 0) {
            int b = dv[j] >> BUCKET_SHIFT;
            int idx = atomicAdd(&hist[b], 1);
            sorted[base_s[b] + idx] = ((dv[j] & 511) << 17) | sv[j];
        }
    }
}

// ---------------- per-bucket: degree, dis, row (start,end), CSR fill — one kernel ----------------
__global__ __launch_bounds__(256) void bucket_build_kernel(const int* __restrict__ sorted,
                                                           const int* __restrict__ gcur,
                                                           int2* __restrict__ rs2,
                                                           float* __restrict__ dis,
                                                           int* __restrict__ csr_src) {
    __shared__ int cnt[512];
    __shared__ int excl[512];
    __shared__ int ps[256];
    int b = blockIdx.x, tid = threadIdx.x;
    cnt[tid] = 0; cnt[tid + 256] = 0;
    __syncthreads();
    int node0 = b << BUCKET_SHIFT;
    int lo = b * CAP, hi = gcur[b];
    for (int i = lo + tid; i < hi; i += 256)
        atomicAdd(&cnt[((unsigned)sorted[i]) >> 17], 1);
    __syncthreads();
    // pair-scan of 512 counts with 256 threads
    int c0 = cnt[2 * tid], c1 = cnt[2 * tid + 1];
    ps[tid] = c0 + c1;
    __syncthreads();
#pragma unroll
    for (int off = 1; off < 256; off <<= 1) {
        int t = (tid >= off) ? ps[tid - off] : 0;
        __syncthreads();
        ps[tid] += t;
        __syncthreads();
    }
    int pex = ps[tid] - (c0 + c1);
    excl[2 * tid] = pex;
    excl[2 * tid + 1] = pex + c0;
    __syncthreads();
#pragma unroll
    for (int k = 0; k < 2; k++) {
        int li = tid + k * 256;
        int node = node0 + li;
        if (node < N_NODES) {
            int st = lo + excl[li];
            int c = cnt[li];
            rs2[node] = make_int2(st, st + c);
            dis[node] = rsqrtf((float)c + 1.0f);
        }
    }
    // reuse cnt as fill cursors
    cnt[tid] = 0; cnt[tid + 256] = 0;
    __syncthreads();
    for (int i = lo + tid; i < hi; i += 256) {
        int v = sorted[i];
        int li = ((unsigned)v) >> 17;
        int idx = atomicAdd(&cnt[li], 1);
        csr_src[lo + excl[li] + idx] = v & 0x1FFFF;
    }
}

__global__ void graph_bounds_kernel(const int* __restrict__ batch, int* __restrict__ gstart,
                                    int n, int G) {
    int i = blockIdx.x * blockDim.x + threadIdx.x;
    if (i >= n) return;
    int b = batch[i];
    int prev = (i == 0) ? -1 : batch[i - 1];
    for (int g = prev + 1; g <= b; ++g) gstart[g] = i;
    if (i == n - 1) {
        for (int g = b + 1; g <= G; ++g) gstart[g] = n;
    }
}

// ---------------- MFMA GEMM: C_fp8[r][c] = e4m3( (sum_k A[r][k] W[k][c]) * scale[r] )
template<bool A_FP32>
__global__ __launch_bounds__(256) void gemm_mfma_kernel(const void* __restrict__ Av,
                                                        const __hip_bfloat16* __restrict__ Wt,
                                                        const float* __restrict__ scale,
                                                        unsigned char* __restrict__ C, int nrows) {
    __shared__ float Cs[64 * 132];
    int tid = threadIdx.x;
    int wave = tid >> 6, lane = tid & 63;
    int quad = lane >> 4, l16 = lane & 15;
    int row0 = blockIdx.x * 64;
    int arow = row0 + wave * 16 + l16;
    int arow_c = min(arow, nrows - 1);

    const __hip_bfloat16* A16 = (const __hip_bfloat16*)Av;
    const float* A32 = (const float*)Av;

    f32x4 acc[8];
#pragma unroll
    for (int t = 0; t < 8; t++) acc[t] = (f32x4){0.f, 0.f, 0.f, 0.f};

#pragma unroll
    for (int kt = 0; kt < 4; kt++) {
        int kbase = kt * 32 + quad * 8;
        union { bf16x8 v; __hip_bfloat16 h[8]; uint4 u; } au;
        if (A_FP32) {
            const float* ap = A32 + (size_t)arow_c * 128 + kbase;
            float4 u0 = *(const float4*)ap;
            float4 u1 = *(const float4*)(ap + 4);
            au.h[0] = __float2bfloat16(u0.x); au.h[1] = __float2bfloat16(u0.y);
            au.h[2] = __float2bfloat16(u0.z); au.h[3] = __float2bfloat16(u0.w);
            au.h[4] = __float2bfloat16(u1.x); au.h[5] = __float2bfloat16(u1.y);
            au.h[6] = __float2bfloat16(u1.z); au.h[7] = __float2bfloat16(u1.w);
        } else {
            au.u = *(const uint4*)(A16 + (size_t)arow_c * 128 + kbase);
        }
#pragma unroll
        for (int t = 0; t < 8; t++) {
            bf16x8 b = *(const bf16x8*)(Wt + (size_t)(t * 16 + l16) * 128 + kbase);
            acc[t] = __builtin_amdgcn_mfma_f32_16x16x32_bf16(au.v, b, acc[t], 0, 0, 0);
        }
    }

    int rbase = wave * 16 + quad * 4;
    float s[4];
#pragma unroll
    for (int r = 0; r < 4; r++) s[r] = scale[min(row0 + rbase + r, nrows - 1)];
#pragma unroll
    for (int t = 0; t < 8; t++) {
#pragma unroll
        for (int r = 0; r < 4; r++)
            Cs[(rbase + r) * 132 + t * 16 + l16] = acc[t][r] * s[r];
    }
    __syncthreads();

#pragma unroll
    for (int p = 0; p < 4; p++) {
        int g = p * 256 + tid;
        int row = g >> 4, c8 = (g & 15) * 8;
        int grow = row0 + row;
        if (grow < nrows) {
            const float* cp = &Cs[row * 132 + c8];
            float4 v0 = *(const float4*)cp;
            float4 v1 = *(const float4*)(cp + 4);
            int w0 = __builtin_amdgcn_cvt_pk_fp8_f32(v0.x, v0.y, 0, false);
            w0 = __builtin_amdgcn_cvt_pk_fp8_f32(v0.z, v0.w, w0, true);
            int w1 = __builtin_amdgcn_cvt_pk_fp8_f32(v1.x, v1.y, 0, false);
            w1 = __builtin_amdgcn_cvt_pk_fp8_f32(v1.z, v1.w, w1, true);
            *(uint2*)(C + (size_t)grow * 128 + c8) = make_uint2((unsigned)w0, (unsigned)w1);
        }
    }
}

// ---------------- GCN aggregation: 4 edges per gather instruction ----------------
// lane = q*16 + f : quarter q handles edge i+q, lane covers features f*8..f*8+7 (8 fp8 = 8 B)
__global__ __launch_bounds__(256) void agg_kernel(const unsigned char* __restrict__ h8,
                                                  const float* __restrict__ dis,
                                                  const int2* __restrict__ rs2,
                                                  const int* __restrict__ csr_src,
                                                  const float* __restrict__ bias,
                                                  __hip_bfloat16* __restrict__ out, int n) {
    int node = blockIdx.x * 4 + (threadIdx.x >> 6);
    if (node >= n) return;
    int lane = threadIdx.x & 63;
    int q = lane >> 4, f = lane & 15;
    float acc[8];
#pragma unroll
    for (int j = 0; j < 8; j++) acc[j] = 0.f;
    int2 se = rs2[node];
    int i = se.x, i1 = se.y;
    // main loop: 4 edges per iteration, no predication
    for (; i + 4 <= i1; i += 4) {
        int s = csr_src[i + q];
        uint2 u = *(const uint2*)(h8 + (size_t)s * 128 + f * 8);
        f32x2 d0 = __builtin_amdgcn_cvt_pk_f32_fp8((int)u.x, false);
        f32x2 d1 = __builtin_amdgcn_cvt_pk_f32_fp8((int)u.x, true);
        f32x2 d2 = __builtin_amdgcn_cvt_pk_f32_fp8((int)u.y, false);
        f32x2 d3 = __builtin_amdgcn_cvt_pk_f32_fp8((int)u.y, true);
        acc[0] += d0[0]; acc[1] += d0[1]; acc[2] += d1[0]; acc[3] += d1[1];
        acc[4] += d2[0]; acc[5] += d2[1]; acc[6] += d3[0]; acc[7] += d3[1];
    }
    // tail: up to 3 edges, predicated
    if (i < i1) {
        bool valid = (i + q) < i1;
        int e = valid ? (i + q) : (i1 - 1);
        int s = csr_src[e];
        uint2 u = *(const uint2*)(h8 + (size_t)s * 128 + f * 8);
        if (valid) {
            f32x2 d0 = __builtin_amdgcn_cvt_pk_f32_fp8((int)u.x, false);
            f32x2 d1 = __builtin_amdgcn_cvt_pk_f32_fp8((int)u.x, true);
            f32x2 d2 = __builtin_amdgcn_cvt_pk_f32_fp8((int)u.y, false);
            f32x2 d3 = __builtin_amdgcn_cvt_pk_f32_fp8((int)u.y, true);
            acc[0] += d0[0]; acc[1] += d0[1]; acc[2] += d1[0]; acc[3] += d1[1];
            acc[4] += d2[0]; acc[5] += d2[1]; acc[6] += d3[0]; acc[7] += d3[1];
        }
    }
    // self term in quarter 0
    if (q == 0) {
        uint2 u = *(const uint2*)(h8 + (size_t)node * 128 + f * 8);
        f32x2 d0 = __builtin_amdgcn_cvt_pk_f32_fp8((int)u.x, false);
        f32x2 d1 = __builtin_amdgcn_cvt_pk_f32_fp8((int)u.x, true);
        f32x2 d2 = __builtin_amdgcn_cvt_pk_f32_fp8((int)u.y, false);
        f32x2 d3 = __builtin_amdgcn_cvt_pk_f32_fp8((int)u.y, true);
        acc[0] += d0[0]; acc[1] += d0[1]; acc[2] += d1[0]; acc[3] += d1[1];
        acc[4] += d2[0]; acc[5] += d2[1]; acc[6] += d3[0]; acc[7] += d3[1];
    }
    // combine quarters: lanes f, f+16, f+32, f+48 -> lane f
#pragma unroll
    for (int j = 0; j < 8; j++) {
        float v = acc[j];
        v += __shfl_down(v, 32, 64);
        v += __shfl_down(v, 16, 64);
        acc[j] = v;
    }
    if (q == 0) {
        float dn = dis[node];
        float4 b0 = *(const float4*)(bias + f * 8);
        float4 b1 = *(const float4*)(bias + f * 8 + 4);
        float r0 = fmaxf(fmaf(acc[0], dn, b0.x), 0.f);
        float r1 = fmaxf(fmaf(acc[1], dn, b0.y), 0.f);
        float r2 = fmaxf(fmaf(acc[2], dn, b0.z), 0.f);
        float r3 = fmaxf(fmaf(acc[3], dn, b0.w), 0.f);
        float r4 = fmaxf(fmaf(acc[4], dn, b1.x), 0.f);
        float r5 = fmaxf(fmaf(acc[5], dn, b1.y), 0.f);
        float r6 = fmaxf(fmaf(acc[6], dn, b1.z), 0.f);
        float r7 = fmaxf(fmaf(acc[7], dn, b1.w), 0.f);
        __hip_bfloat162 p0 = __float22bfloat162_rn(make_float2(r0, r1));
        __hip_bfloat162 p1 = __float22bfloat162_rn(make_float2(r2, r3));
        __hip_bfloat162 p2 = __float22bfloat162_rn(make_float2(r4, r5));
        __hip_bfloat162 p3 = __float22bfloat162_rn(make_float2(r6, r7));
        uint4 pk;
        pk.x = *(unsigned int*)&p0; pk.y = *(unsigned int*)&p1;
        pk.z = *(unsigned int*)&p2; pk.w = *(unsigned int*)&p3;
        *(uint4*)(out + (size_t)node * 128 + f * 8) = pk;
    }
}

// ---------------- pooling: 128 rows/block, 16B/lane, gstart-based segments ----------------
#define POOL_ROWS 128
__global__ __launch_bounds__(256) void pool_kernel(const __hip_bfloat16* __restrict__ h,
                                                   const int* __restrict__ batch,
                                                   const int* __restrict__ gstart,
                                                   float* __restrict__ psum, int n) {
    __shared__ float red[16 * 128];
    int tid = threadIdx.x;
    int rr = tid >> 4, fg = tid & 15;
    int r0 = blockIdx.x * POOL_ROWS;
    if (r0 >= n) return;
    int r1 = min(n, r0 + POOL_ROWS);
    int g = batch[r0];
    int seg_lo = r0;
    while (seg_lo < r1) {
        while (gstart[g + 1] <= seg_lo) g++;
        int seg_hi = min(r1, gstart[g + 1]);
        float a[8];
#pragma unroll
        for (int j = 0; j < 8; j++) a[j] = 0.f;
        for (int r = seg_lo + rr; r < seg_hi; r += 16) {
            uint4 u = *(const uint4*)(h + (size_t)r * 128 + fg * 8);
            float2 f0 = __bfloat1622float2(*(__hip_bfloat162*)&u.x);
            float2 f1 = __bfloat1622float2(*(__hip_bfloat162*)&u.y);
            float2 f2 = __bfloat1622float2(*(__hip_bfloat162*)&u.z);
            float2 f3 = __bfloat1622float2(*(__hip_bfloat162*)&u.w);
            a[0] += f0.x; a[1] += f0.y; a[2] += f1.x; a[3] += f1.y;
            a[4] += f2.x; a[5] += f2.y; a[6] += f3.x; a[7] += f3.y;
        }
        *(float4*)&red[rr * 128 + fg * 8] = make_float4(a[0], a[1], a[2], a[3]);
        *(float4*)&red[rr * 128 + fg * 8 + 4] = make_float4(a[4], a[5], a[6], a[7]);
        __syncthreads();
        if (tid < 128) {
            float s = 0.f;
#pragma unroll
            for (int k = 0; k < 16; k++) s += red[k * 128 + tid];
            atomicAdd(&psum[g * 128 + tid], s);
        }
        __syncthreads();
        seg_lo = seg_hi;
    }
}

// ---------------- fused final MLP ----------------
__global__ __launch_bounds__(256) void mlp_kernel(const float* __restrict__ psum,
                                                  const int* __restrict__ gstart,
                                                  const float* __restrict__ sv,
                                                  const float* __restrict__ act,
                                                  const float* __restrict__ Wf1,
                                                  const float* __restrict__ bf1,
                                                  const float* __restrict__ Wf2,
                                                  const float* __restrict__ bf2,
                                                  const float* __restrict__ Wo,
                                                  const float* __restrict__ bo,
                                                  float* __restrict__ out) {
    int g = blockIdx.x, tid = threadIdx.x;
    __shared__ float z[224];
    __shared__ float z1[256];
    __shared__ float red[256];
    if (tid < 128) {
        int c = gstart[g + 1] - gstart[g];
        float cnt = fmaxf((float)c, 1.f);
        z[tid] = psum[g * 128 + tid] / cnt;
    } else if (tid < 192) {
        z[tid] = sv[g * 64 + (tid - 128)];
    } else if (tid < 224) {
        z[tid] = act[g * 32 + (tid - 192)];
    }
    __syncthreads();
    float a = bf1[tid];
    for (int k = 0; k < 224; k++) a = fmaf(z[k], Wf1[k * 256 + tid], a);
    z1[tid] = fmaxf(a, 0.f);
    __syncthreads();
    float b = bf2[tid];
    for (int k = 0; k < 256; k++) b = fmaf(z1[k], Wf2[k * 256 + tid], b);
    b = fmaxf(b, 0.f);
    red[tid] = b * Wo[tid];
    __syncthreads();
    for (int off = 128; off > 0; off >>= 1) {
        if (tid < off) red[tid] += red[tid + off];
        __syncthreads();
    }
    if (tid == 0) out[g] = red[0] + bo[0];
}

// ---------------- launch ----------------
extern "C" void kernel_launch(void* const* d_in, const int* in_sizes, int n_in,
                              void* d_out, int out_size, void* d_ws, size_t ws_size,
                              hipStream_t stream) {
    const float* x   = (const float*)d_in[0];
    const int*   eidx = (const int*)d_in[1];
    const int*   batch = (const int*)d_in[2];
    const float* sv  = (const float*)d_in[3];
    const float* act = (const float*)d_in[4];
    const float* W1  = (const float*)d_in[5];
    const float* b1  = (const float*)d_in[6];
    const float* W2  = (const float*)d_in[7];
    const float* b2  = (const float*)d_in[8];
    const float* Wf1 = (const float*)d_in[9];
    const float* bf1 = (const float*)d_in[10];
    const float* Wf2 = (const float*)d_in[11];
    const float* bf2 = (const float*)d_in[12];
    const float* Wo  = (const float*)d_in[13];
    const float* bo  = (const float*)d_in[14];
    float* out = (float*)d_out;

    const int* srcp = eidx;             // edge_index[0]
    const int* dstp = eidx + N_EDGES;   // edge_index[1]

    char* w = (char*)d_ws;
    int* gcur = (int*)w;               w += (size_t)NBUCK * 4;
    float* psum = (float*)w;           w += (size_t)N_GRAPHS * HDIM * 4;
    int2* rs2 = (int2*)w;              w += (size_t)N_NODES * 8;
    float* dis = (float*)w;            w += (size_t)N_NODES * 4;
    int* gstart = (int*)w;             w += (size_t)(N_GRAPHS + 1) * 4;
    w = (char*)(((uintptr_t)w + 255) & ~(uintptr_t)255);
    int* csr_src = (int*)w;            w += (size_t)NBUCK * CAP * 4;
    w = (char*)(((uintptr_t)w + 255) & ~(uintptr_t)255);
    int* sorted = (int*)w;             w += (size_t)NBUCK * CAP * 4;
    w = (char*)(((uintptr_t)w + 255) & ~(uintptr_t)255);
    __hip_bfloat16* Wt1 = (__hip_bfloat16*)w;   w += (size_t)HDIM * HDIM * 2;
    __hip_bfloat16* Wt2 = (__hip_bfloat16*)w;   w += (size_t)HDIM * HDIM * 2;
    w = (char*)(((uintptr_t)w + 255) & ~(uintptr_t)255);
    unsigned char* hbuf = (unsigned char*)w;    w += (size_t)N_NODES * HDIM;      // fp8
    w = (char*)(((uintptr_t)w + 255) & ~(uintptr_t)255);
    __hip_bfloat16* abuf = (__hip_bfloat16*)w;  w += (size_t)N_NODES * HDIM * 2;  // bf16

    init_kernel<<<(NBUCK + N_GRAPHS * HDIM + 255) / 256, 256, 0, stream>>>(gcur, psum);
    transpose_w2_kernel<<<128, 256, 0, stream>>>(W1, W2, Wt1, Wt2);

    scatter_kernel<<<SCAT_NBLK, 256, 0, stream>>>(srcp, dstp, gcur, sorted, N_EDGES);
    bucket_build_kernel<<<NBUCK, 256, 0, stream>>>(sorted, gcur, rs2, dis, csr_src);
    graph_bounds_kernel<<<(N_NODES + 255) / 256, 256, 0, stream>>>(batch, gstart, N_NODES, N_GRAPHS);

    int gemm_blocks = (N_NODES + 63) / 64;
    int agg_blocks = (N_NODES + 3) / 4;

    gemm_mfma_kernel<true><<<gemm_blocks, 256, 0, stream>>>(x, Wt1, dis, hbuf, N_NODES);
    agg_kernel<<<agg_blocks, 256, 0, stream>>>(hbuf, dis, rs2, csr_src, b1, abuf, N_NODES);
    gemm_mfma_kernel<false><<<gemm_blocks, 256, 0, stream>>>(abuf, Wt2, dis, hbuf, N_NODES);
    agg_kernel<<<agg_blocks, 256, 0, stream>>>(hbuf, dis, rs2, csr_src, b2, abuf, N_NODES);

    pool_kernel<<<(N_NODES + POOL_ROWS - 1) / POOL_ROWS, 256, 0, stream>>>(abuf, batch, gstart, psum, N_NODES);
    mlp_kernel<<<N_GRAPHS, 256, 0, stream>>>(psum, gstart, sv, act, Wf1, bf1, Wf2, bf2, Wo, bo, out);
}